// Round 3
// baseline (324.764 us; speedup 1.0000x reference)
//
#include <hip/hip_runtime.h>
#include <hip/hip_bf16.h>

typedef __hip_bfloat16 bf16;
typedef short bf16x8 __attribute__((ext_vector_type(8)));
typedef float f32x4 __attribute__((ext_vector_type(4)));

#define CC 16
#define PP 256
#define DMH 512
#define DIH 1024
#define MM (CC*PP)   /* 4096 rows (c,p) */
#define NST 16
#define NDT 32
#define LOG2E 1.44269504088896f

__device__ __forceinline__ float b2f(bf16 v){ return __bfloat162float(v); }
__device__ __forceinline__ bf16  f2b(float v){ return __float2bfloat16(v); }

__device__ __forceinline__ float geluf(float x){
  float x3 = x*x*x;
  return 0.5f*x*(1.0f + tanhf(0.7978845608028654f*x + 0.035677408136300125f*x3));
}
__device__ __forceinline__ float softplusf(float x){
  if (x > 20.0f) return x;
  return log1pf(expf(x));
}

__device__ __forceinline__ void g2l16(const bf16* g, bf16* l){
  __builtin_amdgcn_global_load_lds(
      (const __attribute__((address_space(1))) void*)g,
      (__attribute__((address_space(3))) void*)(uint32_t)(uintptr_t)l,
      16, 0, 0);
}

// sum over 4 consecutive lanes (a 4-lane group); result valid at group lane 3
__device__ __forceinline__ float group_sum4(float y){
  int t;
  t = __builtin_amdgcn_update_dpp(0, __float_as_int(y), 0x111, 0xf, 0xf, true); // row_shr:1
  y += __int_as_float(t);
  t = __builtin_amdgcn_update_dpp(0, __float_as_int(y), 0x112, 0xf, 0xf, true); // row_shr:2
  y += __int_as_float(t);
  return y;
}

// ---------------- fused prep: casts + conv repack + LDS-tiled transpose + xdb zero ----
__global__ void prep_all(const float* __restrict__ x, const float* __restrict__ in_w,
                         const float* __restrict__ out_w, const float* __restrict__ param_w,
                         const float* __restrict__ conv_w,
                         bf16* __restrict__ xbf, bf16* __restrict__ inwz,
                         bf16* __restrict__ outwb, bf16* __restrict__ pwb,
                         bf16* __restrict__ cwT, bf16* __restrict__ inwT,
                         float4* __restrict__ xdb4)
{
  const int b = blockIdx.x, tid = threadIdx.x;
  if (b < 3136){
    const float* src; bf16* dst; int i;
    if (b < 2048)      { src = x;                       dst = xbf;   i = b*256 + tid; }
    else if (b < 2560) { src = in_w + (size_t)DIH*DMH;  dst = inwz;  i = (b-2048)*256 + tid; }
    else if (b < 3072) { src = out_w;                   dst = outwb; i = (b-2560)*256 + tid; }
    else               { src = param_w;                 dst = pwb;   i = (b-3072)*256 + tid; }
    float4 v = ((const float4*)src)[i];
    bf16 o[4] = {f2b(v.x), f2b(v.y), f2b(v.z), f2b(v.w)};
    *(ushort4*)&dst[(size_t)i*4] = *(const ushort4*)o;
  } else if (b < 7232){
    const size_t idx = (size_t)(b-3136)*256 + tid;      // o*1024 + i
    const float4 v = *(const float4*)(conv_w + idx*4);  // [o][i][tap] -> [tap][o][i]
    cwT[idx]                     = f2b(v.x);
    cwT[(size_t)DIH*DIH   + idx] = f2b(v.y);
    cwT[(size_t)2*DIH*DIH + idx] = f2b(v.z);
    cwT[(size_t)3*DIH*DIH + idx] = f2b(v.w);
  } else if (b < 7360){
    // in_w xi-half [i<1024][m<512] -> inwT [m][i], 64x64 LDS tile
    __shared__ float T[64][65];
    const int b2 = b - 7232;
    const int i0 = (b2 >> 3)*64, m0 = (b2 & 7)*64;
    const int r = tid >> 2, c0 = (tid & 3)*16;
    #pragma unroll
    for (int t = 0; t < 4; t++){
      float4 v = *(const float4*)&in_w[(size_t)(i0 + r)*DMH + m0 + c0 + t*4];
      T[r][c0+t*4+0] = v.x; T[r][c0+t*4+1] = v.y;
      T[r][c0+t*4+2] = v.z; T[r][c0+t*4+3] = v.w;
    }
    __syncthreads();
    bf16 o[16];
    #pragma unroll
    for (int t = 0; t < 16; t++) o[t] = f2b(T[c0 + t][r]);
    *(ushort4*)&inwT[(size_t)(m0 + r)*DIH + i0 + c0]      = *(const ushort4*)&o[0];
    *(ushort4*)&inwT[(size_t)(m0 + r)*DIH + i0 + c0 + 4]  = *(const ushort4*)&o[4];
    *(ushort4*)&inwT[(size_t)(m0 + r)*DIH + i0 + c0 + 8]  = *(const ushort4*)&o[8];
    *(ushort4*)&inwT[(size_t)(m0 + r)*DIH + i0 + c0 + 12] = *(const ushort4*)&o[12];
  } else {
    xdb4[(b-7360)*256 + tid] = make_float4(0.f,0.f,0.f,0.f);
  }
}

// cb2[o] = conv_b[o] + sum_i (sum_k conv_w[o,i,k]) * in_b[i]
__global__ void fold_bias(const float* __restrict__ cw, const float* __restrict__ in_b,
                          const float* __restrict__ conv_b, float* __restrict__ cb2){
  const int o = blockIdx.x;
  const int tid = threadIdx.x;
  float acc = 0.0f;
  #pragma unroll
  for (int t = 0; t < 4; t++){
    int i = tid + t*256;
    const float4 w = *(const float4*)(cw + (size_t)o*4096 + (size_t)i*4);
    acc += (w.x + w.y + w.z + w.w) * in_b[i];
  }
  for (int off = 32; off; off >>= 1) acc += __shfl_down(acc, off);
  __shared__ float ls[4];
  if ((tid & 63) == 0) ls[tid >> 6] = acc;
  __syncthreads();
  if (tid == 0) cb2[o] = conv_b[o] + ls[0] + ls[1] + ls[2] + ls[3];
}

// ---------------- MFMA GEMM: C[m,n] = epi( sum_k A[m,k]*B[n,k] + bias[n] ) -------------
#define TBK 64

template<int EPI, int CONV, int NFRAG>
__launch_bounds__(256)
__global__ void mfma_gemm(const bf16* __restrict__ A, int lda,
                          const bf16* __restrict__ B, int ldb,
                          const float* __restrict__ bias,
                          float* __restrict__ outF,
                          bf16* __restrict__ outB0,
                          int ldo, int K, int azs, int ozs, int kzs)
{
  __shared__ bf16 As[128*TBK];           // 16 KB
  __shared__ bf16 Bs[32*NFRAG*TBK];      // 4/8 KB
  const int tid  = threadIdx.x;
  const int lane = tid & 63;
  const int wave = tid >> 6;
  const int wr = (wave >> 1) * 64;
  const int wc = (wave & 1) * 16 * NFRAG;
  const int mBase = blockIdx.x * 128;
  const int nBase = blockIdx.y * (32*NFRAG);
  A += (size_t)blockIdx.z * azs;
  const int nOff = blockIdx.z * ozs;
  const int koff = blockIdx.z * kzs;

  f32x4 acc[4][NFRAG] = {};

  for (int k0 = 0; k0 < K; k0 += TBK) {
    __syncthreads();
    #pragma unroll
    for (int it = 0; it < 4; it++) {      // As: 1024 chunks of 16B
      const int idx = it*256 + tid;
      const int r = idx >> 3, c16 = idx & 7;
      const bf16* ga;
      if (CONV) {
        const int tap = k0 >> 9, kk = k0 & 511;
        const int m = mBase + r;
        const int cc = m >> 8;
        int p = (m & 255) + tap - 2;
        p = min(max(p, 0), PP-1);
        ga = A + ((size_t)(cc*PP + p))*DMH + kk + c16*8;
      } else {
        ga = A + (size_t)(mBase + r)*lda + koff + k0 + c16*8;
      }
      g2l16(ga, &As[(size_t)idx*8]);
    }
    #pragma unroll
    for (int it = 0; it < NFRAG; it++) {  // Bs: 256*NFRAG chunks of 16B
      const int idx = it*256 + tid;
      const int r = idx >> 3, c16 = idx & 7;
      const bf16* gb = B + (size_t)(nBase + r)*ldb + koff + k0 + c16*8;
      g2l16(gb, &Bs[(size_t)idx*8]);
    }
    __syncthreads();
    #pragma unroll
    for (int ks = 0; ks < 2; ks++) {
      bf16x8 af[4], bfr[NFRAG];
      #pragma unroll
      for (int r = 0; r < 4; r++)
        af[r] = *(const bf16x8*)&As[(wr + r*16 + (lane & 15))*TBK + ks*32 + (lane>>4)*8];
      #pragma unroll
      for (int c = 0; c < NFRAG; c++)
        bfr[c] = *(const bf16x8*)&Bs[(wc + c*16 + (lane & 15))*TBK + ks*32 + (lane>>4)*8];
      #pragma unroll
      for (int r = 0; r < 4; r++)
        #pragma unroll
        for (int c = 0; c < NFRAG; c++)
          acc[r][c] = __builtin_amdgcn_mfma_f32_16x16x32_bf16(af[r], bfr[c], acc[r][c], 0, 0, 0);
    }
  }

  const int col0 = lane & 15;
  const int row0 = (lane >> 4) * 4;
  #pragma unroll
  for (int r = 0; r < 4; r++) {
    #pragma unroll
    for (int c = 0; c < NFRAG; c++) {
      #pragma unroll
      for (int reg = 0; reg < 4; reg++) {
        const int m = mBase + wr + r*16 + row0 + reg;
        const int n = nBase + wc + c*16 + col0;
        const float av = acc[r][c][reg];
        if (EPI == 0) {
          outF[(size_t)m*ldo + n] = av + bias[n];
        } else if (EPI == 1) {
          outB0[(size_t)m*ldo + n] = f2b(geluf(av + bias[n]));
        } else if (EPI == 2) {
          outB0[(size_t)m*ldo + n] = f2b(geluf(geluf(av + bias[n])));
        } else if (EPI == 3) {
          outB0[(size_t)m*ldo + n + nOff] = f2b(av);
        } else {
          const float vv = av + ((blockIdx.z == 0) ? bias[n] : 0.0f);
          atomicAdd(&outF[(size_t)m*ldo + n], vv);
        }
      }
    }
  }
}

// ---------------- single-pass fused scan: single wave, 4 states/lane ----------------
// One WAVE per (16-d-group, c). Lane (dl = tid>>2, ng = tid&3) carries 4 states
// s[n = ng*4+q] for channel d0+dl. Coalescing as in the 16-d 256-thread version
// (32B/row xi,gz,ypre chunks; full 256B xdb rows). No barriers: all LDS hazards
// are in-wave. Per 16-row tile: issue next-tile global loads (T14), dt GEMM with
// dt_w rows in registers, 16-step scan (Bv/Cv as b128 covering 4 states, 2-stage
// DPP reduce over 4 lanes), epilogue, then commit regs -> LDS.
#define DBLK 16
__launch_bounds__(64)
__global__ void scan_fused(const float* __restrict__ xdb, const bf16* __restrict__ xi,
                           const bf16* __restrict__ gz,
                           const float* __restrict__ dt_w, const float* __restrict__ dt_b,
                           const float* __restrict__ A_log, const float* __restrict__ Dp,
                           const float* __restrict__ s0,
                           bf16* __restrict__ ypre, float* __restrict__ state_out)
{
  const int dg = blockIdx.x, c = blockIdx.y;
  const int tid = threadIdx.x;
  const int dl = tid >> 2, ng = tid & 3;
  const int d0 = dg*DBLK;
  const int base_m = c*PP;

  __shared__ float  xdbT[16][68];    // dt_in 0..31 | B 32..47 | C 48..63, +4 pad
  __shared__ float2 pxT[16][18];     // {dt, dt*xi} per (j, d)
  __shared__ ushort xiT[16][24];     // bf16 bits, padded pitch (16B-aligned halves)
  __shared__ ushort gzT[16][24];
  __shared__ float  ybF[16][17];
  __shared__ ushort outT[16][24];
  __shared__ float  DvT[16];

  // dt_w row for d = dl, resident in registers (4x redundant load across ng, L1-hit)
  float4 wreg[8];
  #pragma unroll
  for (int i = 0; i < 8; i++)
    wreg[i] = *(const float4*)&dt_w[(size_t)(d0 + dl)*NDT + i*4];
  if (tid < 16) DvT[tid] = Dp[d0 + tid];
  const float dtb = dt_b[d0 + dl];

  // per-lane 4-state setup: n = ng*4+q for channel d0+dl
  const float4 al = *(const float4*)&A_log[(size_t)(d0 + dl)*NST + ng*4];
  float a2q[4] = { -__expf(al.x)*LOG2E, -__expf(al.y)*LOG2E,
                   -__expf(al.z)*LOG2E, -__expf(al.w)*LOG2E };
  const float4 sv = *(const float4*)&s0[((size_t)c*DIH + d0 + dl)*NST + ng*4];
  float s_0 = sv.x, s_1 = sv.y, s_2 = sv.z, s_3 = sv.w;

  // staging roles
  const ushort* xgsrc = (const ushort*)((tid < 32) ? xi : gz);
  const int xgr = (tid & 31) >> 1, xgh = (tid & 1)*8;
  float4 xr[4];
  uint4  wv;

  // tile 0 load
  #pragma unroll
  for (int i = 0; i < 4; i++){
    const int idx = i*64 + tid;
    xr[i] = *(const float4*)&xdb[(size_t)(base_m + (idx >> 4))*64 + (idx & 15)*4];
  }
  wv = *(const uint4*)&xgsrc[(size_t)(base_m + xgr)*DIH + d0 + xgh];
  // commit tile 0
  #pragma unroll
  for (int i = 0; i < 4; i++){
    const int idx = i*64 + tid;
    *(float4*)&xdbT[idx >> 4][(idx & 15)*4] = xr[i];
  }
  if (tid < 32) *(uint4*)&xiT[xgr][xgh] = wv;
  else          *(uint4*)&gzT[xgr][xgh] = wv;

  for (int g = 0; g < 16; ++g){
    const int m0 = base_m + g*16;
    // issue next-tile global loads early (hidden under dt + scan)
    if (g < 15){
      #pragma unroll
      for (int i = 0; i < 4; i++){
        const int idx = i*64 + tid;
        xr[i] = *(const float4*)&xdb[(size_t)(m0 + 16 + (idx >> 4))*64 + (idx & 15)*4];
      }
      wv = *(const uint4*)&xgsrc[(size_t)(m0 + 16 + xgr)*DIH + d0 + xgh];
    }
    // dt phase: lane computes dt for (j = (tid&3)+4*jj, d = dl)
    #pragma unroll
    for (int jj = 0; jj < 4; jj++){
      const int j = (tid & 3) + jj*4;
      float acc = dtb;
      #pragma unroll
      for (int i = 0; i < 8; i++){
        const float4 xv = *(const float4*)&xdbT[j][i*4];
        acc += xv.x*wreg[i].x + xv.y*wreg[i].y + xv.z*wreg[i].z + xv.w*wreg[i].w;
      }
      acc = softplusf(acc);
      bf16 h; *(ushort*)&h = xiT[j][dl];
      float2 px; px.x = acc; px.y = acc * b2f(h);
      pxT[j][dl] = px;
    }
    // 16-step scan, 4 states per lane
    #pragma unroll
    for (int j = 0; j < 16; j++){
      const float2 px = pxT[j][dl];
      const float4 Bv = *(const float4*)&xdbT[j][32 + ng*4];
      const float4 Cv = *(const float4*)&xdbT[j][48 + ng*4];
      const float e0 = exp2f(px.x * a2q[0]);
      const float e1 = exp2f(px.x * a2q[1]);
      const float e2 = exp2f(px.x * a2q[2]);
      const float e3 = exp2f(px.x * a2q[3]);
      s_0 = s_0*e0 + px.y*Bv.x;
      s_1 = s_1*e1 + px.y*Bv.y;
      s_2 = s_2*e2 + px.y*Bv.z;
      s_3 = s_3*e3 + px.y*Bv.w;
      float y = s_0*Cv.x;
      y = fmaf(s_1, Cv.y, y);
      y = fmaf(s_2, Cv.z, y);
      y = fmaf(s_3, Cv.w, y);
      y = group_sum4(y);                 // valid at ng==3
      if (ng == 3) ybF[j][dl] = y;
    }
    // epilogue: lane -> 4 outputs (j = tid&15, d = (tid>>4)+4i)
    #pragma unroll
    for (int i = 0; i < 4; i++){
      const int j = tid & 15, dd = (tid >> 4) + i*4;
      bf16 gh; *(ushort*)&gh = gzT[j][dd];
      bf16 xh; *(ushort*)&xh = xiT[j][dd];
      bf16 hv = f2b((ybF[j][dd] + DvT[dd]*b2f(xh)) * b2f(gh));
      outT[j][dd] = *(const ushort*)&hv;
    }
    // writer: 32 lanes store 16B halves of the 32B rows
    if (tid < 32){
      const int j = tid >> 1, h = (tid & 1)*8;
      *(uint4*)((ushort*)ypre + (size_t)(m0 + j)*DIH + d0 + h) = *(const uint4*)&outT[j][h];
    }
    // commit next tile (after all reads of current tile; in-wave ordering)
    if (g < 15){
      #pragma unroll
      for (int i = 0; i < 4; i++){
        const int idx = i*64 + tid;
        *(float4*)&xdbT[idx >> 4][(idx & 15)*4] = xr[i];
      }
      if (tid < 32) *(uint4*)&xiT[xgr][xgh] = wv;
      else          *(uint4*)&gzT[xgr][xgh] = wv;
    }
  }
  float4 so; so.x = s_0; so.y = s_1; so.z = s_2; so.w = s_3;
  *(float4*)&state_out[((size_t)c*DIH + d0 + dl)*NST + ng*4] = so;
}

extern "C" void kernel_launch(void* const* d_in, const int* in_sizes, int n_in,
                              void* d_out, int out_size, void* d_ws, size_t ws_size,
                              hipStream_t stream) {
  const float* x       = (const float*)d_in[0];
  const float* s0      = (const float*)d_in[1];
  const float* in_w    = (const float*)d_in[2];
  const float* in_b    = (const float*)d_in[3];
  const float* conv_w  = (const float*)d_in[4];
  const float* conv_b  = (const float*)d_in[5];
  const float* param_w = (const float*)d_in[6];
  const float* param_b = (const float*)d_in[7];
  const float* dt_w    = (const float*)d_in[8];
  const float* dt_b    = (const float*)d_in[9];
  const float* out_w   = (const float*)d_in[10];
  const float* out_b   = (const float*)d_in[11];
  const float* A_log   = (const float*)d_in[12];
  const float* Dp      = (const float*)d_in[13];

  char* ws = (char*)d_ws;
  bf16*   xi    = (bf16*)ws;   ws += (size_t)MM*DIH*2;     //  8 MB
  bf16*   gz    = (bf16*)ws;   ws += (size_t)MM*DIH*2;     //  8 MB
  float*  xdb   = (float*)ws;  ws += (size_t)MM*64*4;      //  1 MB
  float*  cb2   = (float*)ws;  ws += 4096;                 //  4 KB
  bf16*   ypre  = (bf16*)ws;   ws += (size_t)MM*DIH*2;     //  8 MB
  bf16*   outwb = (bf16*)ws;   ws += (size_t)DMH*DIH*2;    //  1 MB
  bf16*   pwb   = (bf16*)ws;   ws += (size_t)64*DIH*2;     // 128 KB
  char*   U     = ws;          ws += (size_t)32*1024*1024; // union region, 32 MB
  // early-phase tenants of U (all dead before scan_fused):
  bf16* Wfb  = (bf16*)(U);
  bf16* xbf  = (bf16*)(U + (size_t) 4*1024*1024);
  bf16* inwz = (bf16*)(U + (size_t) 8*1024*1024);
  bf16* inwT = (bf16*)(U + (size_t) 9*1024*1024);
  bf16* cwT  = (bf16*)(U + (size_t)10*1024*1024);

  float* y_out  = (float*)d_out;                           // [C,P,DM] fp32
  float* st_out = y_out + (size_t)MM*DMH;                  // [C,DI,16] fp32

  // fused prep (casts, conv repack, tiled transpose, xdb zero) + fold_bias
  prep_all<<<7616, 256, 0, stream>>>(x, in_w, out_w, param_w, conv_w,
                                     xbf, inwz, outwb, pwb, cwT, inwT, (float4*)xdb);
  fold_bias<<<DIH, 256, 0, stream>>>(conv_w, in_b, conv_b, cb2);

  // fold: Wf[k][o][m] = sum_i conv_w[o,i,k]*in_w[i,m]   (4 taps via grid.z)
  mfma_gemm<3,0,2><<<dim3(DIH/128, DMH/64, 4), 256, 0, stream>>>(
      cwT, DIH, inwT, DIH, nullptr, nullptr, Wfb, 4*DMH, DIH, DIH*DIH, DMH, 0);
  // z-half in_proj: gelu(gelu(x @ in_w_z^T + b_z)) -> gz (contiguous bf16)
  mfma_gemm<2,0,2><<<dim3(MM/128, DIH/64), 256, 0, stream>>>(
      xbf, DMH, inwz, DMH, in_b + DIH, nullptr, gz, DIH, DMH, 0, 0, 0);
  // fused conv: gelu( sum_tap x[clamp] @ Wf_tap^T + cb2 ) -> xi (contiguous bf16)
  mfma_gemm<1,1,2><<<dim3(MM/128, DIH/64), 256, 0, stream>>>(
      xbf, DMH, Wfb, 4*DMH, cb2, nullptr, xi, DIH, 4*DMH, 0, 0, 0);
  // x_db = xi @ param_w.T + param_b   (MFMA split-K=8, fp32 atomics into zeroed xdb)
  mfma_gemm<4,0,2><<<dim3(MM/128, 1, 8), 256, 0, stream>>>(
      xi, DIH, pwb, DIH, param_b, xdb, nullptr, 64, 128, 0, 0, 128);
  // single-wave single-pass fused scan, 4 states/lane
  scan_fused<<<dim3(DIH/DBLK, CC), 64, 0, stream>>>(xdb, xi, gz, dt_w, dt_b, A_log, Dp,
                                                    s0, ypre, st_out);
  // out projection
  mfma_gemm<0,0,1><<<dim3(MM/128, DMH/32), 256, 0, stream>>>(
      ypre, DIH, outwb, DIH, out_b, y_out, nullptr, DMH, DIH, 0, 0, 0);
}

// Round 4
// 296.658 us; speedup vs baseline: 1.0947x; 1.0947x over previous
//
#include <hip/hip_runtime.h>
#include <hip/hip_bf16.h>

typedef __hip_bfloat16 bf16;
typedef short bf16x8 __attribute__((ext_vector_type(8)));
typedef float f32x4 __attribute__((ext_vector_type(4)));

#define CC 16
#define PP 256
#define DMH 512
#define DIH 1024
#define MM (CC*PP)   /* 4096 rows (c,p) */
#define NST 16
#define NDT 32
#define LOG2E 1.44269504088896f

__device__ __forceinline__ float b2f(bf16 v){ return __bfloat162float(v); }
__device__ __forceinline__ bf16  f2b(float v){ return __float2bfloat16(v); }

__device__ __forceinline__ float geluf(float x){
  float x3 = x*x*x;
  return 0.5f*x*(1.0f + tanhf(0.7978845608028654f*x + 0.035677408136300125f*x3));
}
__device__ __forceinline__ float softplusf(float x){
  if (x > 20.0f) return x;
  return log1pf(expf(x));
}

__device__ __forceinline__ void g2l16(const bf16* g, bf16* l){
  __builtin_amdgcn_global_load_lds(
      (const __attribute__((address_space(1))) void*)g,
      (__attribute__((address_space(3))) void*)(uint32_t)(uintptr_t)l,
      16, 0, 0);
}

// sum over the 16 lanes of a DPP row; result valid at lane (row_base+15)
__device__ __forceinline__ float row_sum16(float y){
  int t;
  t = __builtin_amdgcn_update_dpp(0, __float_as_int(y), 0x111, 0xf, 0xf, true); // row_shr:1
  y += __int_as_float(t);
  t = __builtin_amdgcn_update_dpp(0, __float_as_int(y), 0x112, 0xf, 0xf, true); // row_shr:2
  y += __int_as_float(t);
  t = __builtin_amdgcn_update_dpp(0, __float_as_int(y), 0x114, 0xf, 0xf, true); // row_shr:4
  y += __int_as_float(t);
  t = __builtin_amdgcn_update_dpp(0, __float_as_int(y), 0x118, 0xf, 0xf, true); // row_shr:8
  y += __int_as_float(t);
  return y;
}

// ---------------- fused prep: casts + conv repack + LDS-tiled transpose + xdb zero ----
__global__ void prep_all(const float* __restrict__ x, const float* __restrict__ in_w,
                         const float* __restrict__ out_w, const float* __restrict__ param_w,
                         const float* __restrict__ conv_w, const float* __restrict__ dt_w,
                         bf16* __restrict__ xbf, bf16* __restrict__ inwz,
                         bf16* __restrict__ outwb, bf16* __restrict__ pwb,
                         bf16* __restrict__ cwT, bf16* __restrict__ inwT,
                         bf16* __restrict__ dtwb,
                         float4* __restrict__ xdb4)
{
  const int b = blockIdx.x, tid = threadIdx.x;
  if (b < 3136){
    const float* src; bf16* dst; int i;
    if (b < 2048)      { src = x;                       dst = xbf;   i = b*256 + tid; }
    else if (b < 2560) { src = in_w + (size_t)DIH*DMH;  dst = inwz;  i = (b-2048)*256 + tid; }
    else if (b < 3072) { src = out_w;                   dst = outwb; i = (b-2560)*256 + tid; }
    else               { src = param_w;                 dst = pwb;   i = (b-3072)*256 + tid; }
    float4 v = ((const float4*)src)[i];
    bf16 o[4] = {f2b(v.x), f2b(v.y), f2b(v.z), f2b(v.w)};
    *(ushort4*)&dst[(size_t)i*4] = *(const ushort4*)o;
  } else if (b < 7232){
    const size_t idx = (size_t)(b-3136)*256 + tid;      // o*1024 + i
    const float4 v = *(const float4*)(conv_w + idx*4);  // [o][i][tap] -> [tap][o][i]
    cwT[idx]                     = f2b(v.x);
    cwT[(size_t)DIH*DIH   + idx] = f2b(v.y);
    cwT[(size_t)2*DIH*DIH + idx] = f2b(v.z);
    cwT[(size_t)3*DIH*DIH + idx] = f2b(v.w);
  } else if (b < 7360){
    // in_w xi-half [i<1024][m<512] -> inwT [m][i], 64x64 LDS tile
    __shared__ float T[64][65];
    const int b2 = b - 7232;
    const int i0 = (b2 >> 3)*64, m0 = (b2 & 7)*64;
    const int r = tid >> 2, c0 = (tid & 3)*16;
    #pragma unroll
    for (int t = 0; t < 4; t++){
      float4 v = *(const float4*)&in_w[(size_t)(i0 + r)*DMH + m0 + c0 + t*4];
      T[r][c0+t*4+0] = v.x; T[r][c0+t*4+1] = v.y;
      T[r][c0+t*4+2] = v.z; T[r][c0+t*4+3] = v.w;
    }
    __syncthreads();
    bf16 o[16];
    #pragma unroll
    for (int t = 0; t < 16; t++) o[t] = f2b(T[c0 + t][r]);
    *(ushort4*)&inwT[(size_t)(m0 + r)*DIH + i0 + c0]      = *(const ushort4*)&o[0];
    *(ushort4*)&inwT[(size_t)(m0 + r)*DIH + i0 + c0 + 4]  = *(const ushort4*)&o[4];
    *(ushort4*)&inwT[(size_t)(m0 + r)*DIH + i0 + c0 + 8]  = *(const ushort4*)&o[8];
    *(ushort4*)&inwT[(size_t)(m0 + r)*DIH + i0 + c0 + 12] = *(const ushort4*)&o[12];
  } else if (b < 7616){
    xdb4[(b-7360)*256 + tid] = make_float4(0.f,0.f,0.f,0.f);
  } else {
    // dt_w [1024][32] fp32 -> dtwb [1024][64] bf16, cols 32..63 zero (K=64 pad)
    const int idx4 = (b-7616)*256 + tid;          // 0..16383
    const int d = idx4 >> 4, k4 = (idx4 & 15)*4;
    bf16 o[4] = {};
    if (k4 < 32){
      const float4 v = *(const float4*)&dt_w[(size_t)d*NDT + k4];
      o[0]=f2b(v.x); o[1]=f2b(v.y); o[2]=f2b(v.z); o[3]=f2b(v.w);
    }
    *(ushort4*)&dtwb[(size_t)d*64 + k4] = *(const ushort4*)o;
  }
}

// xdb [4096][64] fp32 -> xdbb [4096][64] bf16 with cols 32..63 zeroed (dt GEMM A, K=64)
__global__ void cast_xdbb(const float* __restrict__ xdb, bf16* __restrict__ xdbb){
  const int idx = blockIdx.x*256 + threadIdx.x;   // 0..65535
  const int m = idx >> 4, k4 = (idx & 15)*4;
  bf16 o[4] = {};
  if (k4 < 32){
    const float4 v = *(const float4*)&xdb[(size_t)m*64 + k4];
    o[0]=f2b(v.x); o[1]=f2b(v.y); o[2]=f2b(v.z); o[3]=f2b(v.w);
  }
  *(ushort4*)&xdbb[(size_t)m*64 + k4] = *(const ushort4*)o;
}

// cb2[o] = conv_b[o] + sum_i (sum_k conv_w[o,i,k]) * in_b[i]
__global__ void fold_bias(const float* __restrict__ cw, const float* __restrict__ in_b,
                          const float* __restrict__ conv_b, float* __restrict__ cb2){
  const int o = blockIdx.x;
  const int tid = threadIdx.x;
  float acc = 0.0f;
  #pragma unroll
  for (int t = 0; t < 4; t++){
    int i = tid + t*256;
    const float4 w = *(const float4*)(cw + (size_t)o*4096 + (size_t)i*4);
    acc += (w.x + w.y + w.z + w.w) * in_b[i];
  }
  for (int off = 32; off; off >>= 1) acc += __shfl_down(acc, off);
  __shared__ float ls[4];
  if ((tid & 63) == 0) ls[tid >> 6] = acc;
  __syncthreads();
  if (tid == 0) cb2[o] = conv_b[o] + ls[0] + ls[1] + ls[2] + ls[3];
}

// ---------------- MFMA GEMM: C[m,n] = epi( sum_k A[m,k]*B[n,k] + bias[n] ) -------------
#define TBK 64

template<int EPI, int CONV, int NFRAG>
__launch_bounds__(256)
__global__ void mfma_gemm(const bf16* __restrict__ A, int lda,
                          const bf16* __restrict__ B, int ldb,
                          const float* __restrict__ bias,
                          float* __restrict__ outF,
                          bf16* __restrict__ outB0,
                          int ldo, int K, int azs, int ozs, int kzs)
{
  __shared__ bf16 As[128*TBK];           // 16 KB
  __shared__ bf16 Bs[32*NFRAG*TBK];      // 4/8 KB
  const int tid  = threadIdx.x;
  const int lane = tid & 63;
  const int wave = tid >> 6;
  const int wr = (wave >> 1) * 64;
  const int wc = (wave & 1) * 16 * NFRAG;
  const int mBase = blockIdx.x * 128;
  const int nBase = blockIdx.y * (32*NFRAG);
  A += (size_t)blockIdx.z * azs;
  const int nOff = blockIdx.z * ozs;
  const int koff = blockIdx.z * kzs;

  f32x4 acc[4][NFRAG] = {};

  for (int k0 = 0; k0 < K; k0 += TBK) {
    __syncthreads();
    #pragma unroll
    for (int it = 0; it < 4; it++) {      // As: 1024 chunks of 16B
      const int idx = it*256 + tid;
      const int r = idx >> 3, c16 = idx & 7;
      const bf16* ga;
      if (CONV) {
        const int tap = k0 >> 9, kk = k0 & 511;
        const int m = mBase + r;
        const int cc = m >> 8;
        int p = (m & 255) + tap - 2;
        p = min(max(p, 0), PP-1);
        ga = A + ((size_t)(cc*PP + p))*DMH + kk + c16*8;
      } else {
        ga = A + (size_t)(mBase + r)*lda + koff + k0 + c16*8;
      }
      g2l16(ga, &As[(size_t)idx*8]);
    }
    #pragma unroll
    for (int it = 0; it < NFRAG; it++) {  // Bs: 256*NFRAG chunks of 16B
      const int idx = it*256 + tid;
      const int r = idx >> 3, c16 = idx & 7;
      const bf16* gb = B + (size_t)(nBase + r)*ldb + koff + k0 + c16*8;
      g2l16(gb, &Bs[(size_t)idx*8]);
    }
    __syncthreads();
    #pragma unroll
    for (int ks = 0; ks < 2; ks++) {
      bf16x8 af[4], bfr[NFRAG];
      #pragma unroll
      for (int r = 0; r < 4; r++)
        af[r] = *(const bf16x8*)&As[(wr + r*16 + (lane & 15))*TBK + ks*32 + (lane>>4)*8];
      #pragma unroll
      for (int c = 0; c < NFRAG; c++)
        bfr[c] = *(const bf16x8*)&Bs[(wc + c*16 + (lane & 15))*TBK + ks*32 + (lane>>4)*8];
      #pragma unroll
      for (int r = 0; r < 4; r++)
        #pragma unroll
        for (int c = 0; c < NFRAG; c++)
          acc[r][c] = __builtin_amdgcn_mfma_f32_16x16x32_bf16(af[r], bfr[c], acc[r][c], 0, 0, 0);
    }
  }

  const int col0 = lane & 15;
  const int row0 = (lane >> 4) * 4;
  #pragma unroll
  for (int r = 0; r < 4; r++) {
    #pragma unroll
    for (int c = 0; c < NFRAG; c++) {
      #pragma unroll
      for (int reg = 0; reg < 4; reg++) {
        const int m = mBase + wr + r*16 + row0 + reg;
        const int n = nBase + wc + c*16 + col0;
        const float av = acc[r][c][reg];
        if (EPI == 0) {
          outF[(size_t)m*ldo + n] = av + bias[n];
        } else if (EPI == 1) {
          outB0[(size_t)m*ldo + n] = f2b(geluf(av + bias[n]));
        } else if (EPI == 2) {
          outB0[(size_t)m*ldo + n] = f2b(geluf(geluf(av + bias[n])));
        } else if (EPI == 3) {
          outB0[(size_t)m*ldo + n + nOff] = f2b(av);
        } else if (EPI == 5) {
          // dt = softplus(av + dt_b[n]); pack {dt, dt*xi} as bf16 pair -> uint plane
          const float dtv = softplusf(av + bias[n]);
          const ushort ux = ((const ushort*)outF)[(size_t)m*DIH + n];  // xi bits
          bf16 xh; *(ushort*)&xh = ux;
          bf16 dA = f2b(dtv);
          bf16 dB = f2b(dtv * b2f(xh));
          const uint pk = (uint)(*(const ushort*)&dA) | ((uint)(*(const ushort*)&dB) << 16);
          ((uint*)outB0)[(size_t)m*ldo + n] = pk;
        } else {
          const float vv = av + ((blockIdx.z == 0) ? bias[n] : 0.0f);
          atomicAdd(&outF[(size_t)m*ldo + n], vv);
        }
      }
    }
  }
}

// ---------------- single-pass fused scan v4: cooperative 4-wave, dt pre-GEMMed --------
// Block 256 (16 d x 16 n), grid (64 dg, 16 c). dt and dt*xi come precomputed in the
// packed uint plane pxg (bf16 pair) -> no dt phase, no dt_w staging. Triple-buffered
// tile staging (reg prefetch issued at tile start, committed after scan reads) gives
// ONE barrier per tile. ybF double-buffered to avoid the cross-wave race; outT relay
// and ypre write are wave-local after the barrier.
__launch_bounds__(256)
__global__ void scan_v4(const float* __restrict__ xdb, const bf16* __restrict__ xi,
                        const bf16* __restrict__ gz, const uint* __restrict__ pxg,
                        const float* __restrict__ A_log, const float* __restrict__ Dp,
                        const float* __restrict__ s0,
                        bf16* __restrict__ ypre, float* __restrict__ state_out)
{
  const int dg = blockIdx.x, c = blockIdx.y;
  const int tid = threadIdx.x;
  const int n = tid & 15, dl = tid >> 4;
  const int d0 = dg*16;
  const int base_m = c*PP;

  __shared__ float  bcT[3][16][36];   // B 0..15 | C 16..31 (pitch 144B, 16B-mult)
  __shared__ uint   pxT[3][16][20];   // packed {dt(lo), dt*xi(hi)} (pitch 80B)
  __shared__ ushort xgT[3][16][40];   // xi 0..15 | gz 16..31 (pitch 80B)
  __shared__ float  ybF[2][16][17];
  __shared__ ushort outT[16][24];     // pitch 48B
  __shared__ float  DvT[16];

  if (tid < 16) DvT[tid] = Dp[d0 + tid];
  const float a2 = -__expf(A_log[(size_t)(d0 + dl)*NST + n]) * LOG2E;
  float s = s0[((size_t)c*DIH + d0 + dl)*NST + n];

  // staging roles (1 vector load per thread per tile)
  const int sr_bc = tid >> 3, sc_bc = (tid & 7)*4;            // tid < 128
  const int sr_px = (tid - 128) >> 2, sc_px = ((tid-128) & 3)*4; // 128..191
  const int sr_xg = (tid & 31) >> 1, sh_xg = (tid & 1)*8;     // 192..255 (xi / gz)
  float4 bc_r; uint4 px_r; uint4 xg_r;

  // prologue: tile 0 load + commit
  {
    const int m0 = base_m;
    if (tid < 128)      bc_r = *(const float4*)&xdb[(size_t)(m0+sr_bc)*64 + 32 + sc_bc];
    else if (tid < 192) px_r = *(const uint4*)&pxg[(size_t)(m0+sr_px)*DIH + d0 + sc_px];
    else xg_r = *(const uint4*)&((const ushort*)((tid<224)?xi:gz))[(size_t)(m0+sr_xg)*DIH + d0 + sh_xg];
    if (tid < 128)      *(float4*)&bcT[0][sr_bc][sc_bc] = bc_r;
    else if (tid < 192) *(uint4*)&pxT[0][sr_px][sc_px] = px_r;
    else if (tid < 224) *(uint4*)&xgT[0][sr_xg][sh_xg] = xg_r;
    else                *(uint4*)&xgT[0][sr_xg][16+sh_xg] = xg_r;
  }
  __syncthreads();

  for (int g = 0; g < 16; ++g){
    const int buf = g % 3, nb = (g+1) % 3, yb = g & 1;
    const int m0 = base_m + g*16;
    // issue next-tile global loads (latency hides under the scan)
    if (g < 15){
      const int m1 = m0 + 16;
      if (tid < 128)      bc_r = *(const float4*)&xdb[(size_t)(m1+sr_bc)*64 + 32 + sc_bc];
      else if (tid < 192) px_r = *(const uint4*)&pxg[(size_t)(m1+sr_px)*DIH + d0 + sc_px];
      else xg_r = *(const uint4*)&((const ushort*)((tid<224)?xi:gz))[(size_t)(m1+sr_xg)*DIH + d0 + sh_xg];
    }
    // 16-step scan
    #pragma unroll
    for (int j = 0; j < 16; j++){
      const uint pk = pxT[buf][j][dl];
      const float dtv  = __int_as_float(pk << 16);          // lo bf16 -> f32
      const float dtxi = __int_as_float(pk & 0xffff0000u);  // hi bf16 -> f32
      const float Bv = bcT[buf][j][n];
      const float Cv = bcT[buf][j][16 + n];
      const float e = exp2f(dtv * a2);
      s = s*e + dtxi * Bv;
      const float yy = row_sum16(s * Cv);   // valid at n==15
      if (n == 15) ybF[yb][j][dl] = yy;
    }
    // commit next tile into the third buffer (current epilogue still reads buf)
    if (g < 15){
      if (tid < 128)      *(float4*)&bcT[nb][sr_bc][sc_bc] = bc_r;
      else if (tid < 192) *(uint4*)&pxT[nb][sr_px][sc_px] = px_r;
      else if (tid < 224) *(uint4*)&xgT[nb][sr_xg][sh_xg] = xg_r;
      else                *(uint4*)&xgT[nb][sr_xg][16+sh_xg] = xg_r;
    }
    __syncthreads();
    // epilogue: thread (ej=tid>>4, ed=tid&15) -> (m0+ej, d0+ed); all wave-local
    {
      const int ej = tid >> 4, ed = tid & 15;
      bf16 xh; *(ushort*)&xh = xgT[buf][ej][ed];
      bf16 gh; *(ushort*)&gh = xgT[buf][ej][16+ed];
      bf16 hv = f2b((ybF[yb][ej][ed] + DvT[ed]*b2f(xh)) * b2f(gh));
      outT[ej][ed] = *(const ushort*)&hv;
      if (ed < 2)
        *(uint4*)((ushort*)ypre + (size_t)(m0+ej)*DIH + d0 + ed*8) = *(const uint4*)&outT[ej][ed*8];
    }
  }
  state_out[((size_t)c*DIH + d0 + dl)*NST + n] = s;
}

extern "C" void kernel_launch(void* const* d_in, const int* in_sizes, int n_in,
                              void* d_out, int out_size, void* d_ws, size_t ws_size,
                              hipStream_t stream) {
  const float* x       = (const float*)d_in[0];
  const float* s0      = (const float*)d_in[1];
  const float* in_w    = (const float*)d_in[2];
  const float* in_b    = (const float*)d_in[3];
  const float* conv_w  = (const float*)d_in[4];
  const float* conv_b  = (const float*)d_in[5];
  const float* param_w = (const float*)d_in[6];
  const float* param_b = (const float*)d_in[7];
  const float* dt_w    = (const float*)d_in[8];
  const float* dt_b    = (const float*)d_in[9];
  const float* out_w   = (const float*)d_in[10];
  const float* out_b   = (const float*)d_in[11];
  const float* A_log   = (const float*)d_in[12];
  const float* Dp      = (const float*)d_in[13];

  char* ws = (char*)d_ws;
  bf16*   xi    = (bf16*)ws;   ws += (size_t)MM*DIH*2;     //  8 MB
  bf16*   gz    = (bf16*)ws;   ws += (size_t)MM*DIH*2;     //  8 MB
  float*  xdb   = (float*)ws;  ws += (size_t)MM*64*4;      //  1 MB
  float*  cb2   = (float*)ws;  ws += 4096;                 //  4 KB
  bf16*   ypre  = (bf16*)ws;   ws += (size_t)MM*DIH*2;     //  8 MB
  bf16*   outwb = (bf16*)ws;   ws += (size_t)DMH*DIH*2;    //  1 MB
  bf16*   pwb   = (bf16*)ws;   ws += (size_t)64*DIH*2;     // 128 KB
  bf16*   dtwb  = (bf16*)ws;   ws += (size_t)DIH*64*2;     // 128 KB (prep -> px GEMM)
  char*   U     = ws;          ws += (size_t)32*1024*1024; // union region, 32 MB
  // early-phase tenants of U (all dead before cast_xdbb / px GEMM):
  bf16* Wfb  = (bf16*)(U);
  bf16* xbf  = (bf16*)(U + (size_t) 4*1024*1024);
  bf16* inwz = (bf16*)(U + (size_t) 8*1024*1024);
  bf16* inwT = (bf16*)(U + (size_t) 9*1024*1024);
  bf16* cwT  = (bf16*)(U + (size_t)10*1024*1024);
  // late-phase tenants of U:
  bf16* xdbb = (bf16*)(U + (size_t)14*1024*1024);          // 512 KB
  uint* pxg  = (uint*)(U + (size_t)16*1024*1024);          // 16 MB packed {dt, dt*xi}

  float* y_out  = (float*)d_out;                           // [C,P,DM] fp32
  float* st_out = y_out + (size_t)MM*DMH;                  // [C,DI,16] fp32

  // fused prep (casts, conv repack, tiled transpose, xdb zero, dt_w cast) + fold_bias
  prep_all<<<7680, 256, 0, stream>>>(x, in_w, out_w, param_w, conv_w, dt_w,
                                     xbf, inwz, outwb, pwb, cwT, inwT, dtwb,
                                     (float4*)xdb);
  fold_bias<<<DIH, 256, 0, stream>>>(conv_w, in_b, conv_b, cb2);

  // fold: Wf[k][o][m] = sum_i conv_w[o,i,k]*in_w[i,m]   (4 taps via grid.z)
  mfma_gemm<3,0,2><<<dim3(DIH/128, DMH/64, 4), 256, 0, stream>>>(
      cwT, DIH, inwT, DIH, nullptr, nullptr, Wfb, 4*DMH, DIH, DIH*DIH, DMH, 0);
  // z-half in_proj: gelu(gelu(x @ in_w_z^T + b_z)) -> gz (contiguous bf16)
  mfma_gemm<2,0,2><<<dim3(MM/128, DIH/64), 256, 0, stream>>>(
      xbf, DMH, inwz, DMH, in_b + DIH, nullptr, gz, DIH, DMH, 0, 0, 0);
  // fused conv: gelu( sum_tap x[clamp] @ Wf_tap^T + cb2 ) -> xi (contiguous bf16)
  mfma_gemm<1,1,2><<<dim3(MM/128, DIH/64), 256, 0, stream>>>(
      xbf, DMH, Wfb, 4*DMH, cb2, nullptr, xi, DIH, 4*DMH, 0, 0, 0);
  // x_db = xi @ param_w.T + param_b   (MFMA split-K=8, fp32 atomics into zeroed xdb)
  mfma_gemm<4,0,2><<<dim3(MM/128, 1, 8), 256, 0, stream>>>(
      xi, DIH, pwb, DIH, param_b, xdb, nullptr, 64, 128, 0, 0, 128);
  // dt offload: cast xdb[:, :32] to bf16 (K=64 zero-padded), then
  // pxg[m][d] = pack{ softplus(dt_in @ dt_w^T + dt_b), dt * xi }  via MFMA
  cast_xdbb<<<256, 256, 0, stream>>>(xdb, xdbb);
  mfma_gemm<5,0,2><<<dim3(MM/128, DIH/64), 256, 0, stream>>>(
      xdbb, 64, dtwb, 64, dt_b, (float*)xi, (bf16*)pxg, DIH, 64, 0, 0, 0);
  // cooperative single-pass fused scan (1 barrier/tile, dt pre-GEMMed)
  scan_v4<<<dim3(64, CC), 256, 0, stream>>>(xdb, xi, gz, pxg, A_log, Dp,
                                            s0, ypre, st_out);
  // out projection
  mfma_gemm<0,0,1><<<dim3(MM/128, DMH/32), 256, 0, stream>>>(
      ypre, DIH, outwb, DIH, out_b, y_out, nullptr, DMH, DIH, 0, 0, 0);
}

// Round 5
// 262.702 us; speedup vs baseline: 1.2362x; 1.1293x over previous
//
#include <hip/hip_runtime.h>
#include <hip/hip_bf16.h>

typedef __hip_bfloat16 bf16;
typedef short bf16x8 __attribute__((ext_vector_type(8)));
typedef float f32x4 __attribute__((ext_vector_type(4)));

#define CC 16
#define PP 256
#define DMH 512
#define DIH 1024
#define MM (CC*PP)   /* 4096 rows (c,p) */
#define NST 16
#define NDT 32
#define LOG2E 1.44269504088896f

__device__ __forceinline__ float b2f(bf16 v){ return __bfloat162float(v); }
__device__ __forceinline__ bf16  f2b(float v){ return __float2bfloat16(v); }

// fast tanh-gelu: tanh(u) = 1 - 2/(exp(2u)+1); exact limits at +-inf
__device__ __forceinline__ float geluf(float x){
  const float u = x*(0.7978845608028654f + 0.035677408136300125f*x*x);
  const float e = exp2f(2.885390081777927f*u);            // exp(2u)
  const float t = 1.0f - 2.0f*__builtin_amdgcn_rcpf(e + 1.0f);
  return 0.5f*x*(1.0f + t);
}
__device__ __forceinline__ float softplusf(float x){
  if (x > 20.0f) return x;
  return log1pf(expf(x));
}

__device__ __forceinline__ void g2l16(const bf16* g, bf16* l){
  __builtin_amdgcn_global_load_lds(
      (const __attribute__((address_space(1))) void*)g,
      (__attribute__((address_space(3))) void*)(uint32_t)(uintptr_t)l,
      16, 0, 0);
}

// ---------------- fused prep: casts + conv repack (+cb2 fold) + transpose + dtw cast --
__global__ void prep_all(const float* __restrict__ x, const float* __restrict__ in_w,
                         const float* __restrict__ out_w, const float* __restrict__ param_w,
                         const float* __restrict__ conv_w, const float* __restrict__ dt_w,
                         const float* __restrict__ in_b, const float* __restrict__ conv_b,
                         float* __restrict__ cb2,
                         bf16* __restrict__ xbf, bf16* __restrict__ inwz,
                         bf16* __restrict__ outwb, bf16* __restrict__ pwb,
                         bf16* __restrict__ cwT, bf16* __restrict__ inwT,
                         bf16* __restrict__ dtwb)
{
  const int b = blockIdx.x, tid = threadIdx.x;
  if (b < 3136){
    const float* src; bf16* dst; int i;
    if (b < 2048)      { src = x;                       dst = xbf;   i = b*256 + tid; }
    else if (b < 2560) { src = in_w + (size_t)DIH*DMH;  dst = inwz;  i = (b-2048)*256 + tid; }
    else if (b < 3072) { src = out_w;                   dst = outwb; i = (b-2560)*256 + tid; }
    else               { src = param_w;                 dst = pwb;   i = (b-3072)*256 + tid; }
    float4 v = ((const float4*)src)[i];
    bf16 o[4] = {f2b(v.x), f2b(v.y), f2b(v.z), f2b(v.w)};
    *(ushort4*)&dst[(size_t)i*4] = *(const ushort4*)o;
  } else if (b < 7232){
    const size_t idx = (size_t)(b-3136)*256 + tid;      // o*1024 + i
    const float4 v = *(const float4*)(conv_w + idx*4);  // [o][i][tap] -> [tap][o][i]
    cwT[idx]                     = f2b(v.x);
    cwT[(size_t)DIH*DIH   + idx] = f2b(v.y);
    cwT[(size_t)2*DIH*DIH + idx] = f2b(v.z);
    cwT[(size_t)3*DIH*DIH + idx] = f2b(v.w);
    // folded bias partial: cb2[o] += sum_i (sum_k w[o,i,k]) * in_b[i]
    __shared__ float ls[4];
    const int i = (int)(idx & 1023);
    float acc = (v.x + v.y + v.z + v.w) * in_b[i];
    for (int off = 32; off; off >>= 1) acc += __shfl_down(acc, off);
    if ((tid & 63) == 0) ls[tid >> 6] = acc;
    __syncthreads();
    if (tid == 0){
      const int o = (int)(idx >> 10);
      float tot = ls[0] + ls[1] + ls[2] + ls[3];
      if (((b - 3136) & 3) == 0) tot += conv_b[o];
      atomicAdd(&cb2[o], tot);
    }
  } else if (b < 7360){
    // in_w xi-half [i<1024][m<512] -> inwT [m][i], 64x64 LDS tile
    __shared__ float T[64][65];
    const int b2 = b - 7232;
    const int i0 = (b2 >> 3)*64, m0 = (b2 & 7)*64;
    const int r = tid >> 2, c0 = (tid & 3)*16;
    #pragma unroll
    for (int t = 0; t < 4; t++){
      float4 v = *(const float4*)&in_w[(size_t)(i0 + r)*DMH + m0 + c0 + t*4];
      T[r][c0+t*4+0] = v.x; T[r][c0+t*4+1] = v.y;
      T[r][c0+t*4+2] = v.z; T[r][c0+t*4+3] = v.w;
    }
    __syncthreads();
    bf16 o[16];
    #pragma unroll
    for (int t = 0; t < 16; t++) o[t] = f2b(T[c0 + t][r]);
    *(ushort4*)&inwT[(size_t)(m0 + r)*DIH + i0 + c0]      = *(const ushort4*)&o[0];
    *(ushort4*)&inwT[(size_t)(m0 + r)*DIH + i0 + c0 + 4]  = *(const ushort4*)&o[4];
    *(ushort4*)&inwT[(size_t)(m0 + r)*DIH + i0 + c0 + 8]  = *(const ushort4*)&o[8];
    *(ushort4*)&inwT[(size_t)(m0 + r)*DIH + i0 + c0 + 12] = *(const ushort4*)&o[12];
  } else {
    // dt_w [1024][32] fp32 -> dtwb [1024][64] bf16, cols 32..63 zero (K=64 pad)
    const int idx4 = (b-7360)*256 + tid;          // 0..16383
    const int d = idx4 >> 4, k4 = (idx4 & 15)*4;
    bf16 o[4] = {};
    if (k4 < 32){
      const float4 v = *(const float4*)&dt_w[(size_t)d*NDT + k4];
      o[0]=f2b(v.x); o[1]=f2b(v.y); o[2]=f2b(v.z); o[3]=f2b(v.w);
    }
    *(ushort4*)&dtwb[(size_t)d*64 + k4] = *(const ushort4*)o;
  }
}

// reduce 8 split-K planes + param_b -> xdbb (bf16 cols 0..31, K=64 pad) + bcg (fp32 B|C)
__global__ void reduce_cast(const float* __restrict__ pxz, const float* __restrict__ param_b,
                            float* __restrict__ bcg, bf16* __restrict__ xdbb){
  const int idx = blockIdx.x*256 + threadIdx.x;   // 0..65535 float4 units
  const int m = idx >> 4, k4 = (idx & 15)*4;
  float4 s = make_float4(0.f,0.f,0.f,0.f);
  #pragma unroll
  for (int z = 0; z < 8; z++){
    const float4 v = *(const float4*)&pxz[(size_t)z*MM*64 + (size_t)m*64 + k4];
    s.x += v.x; s.y += v.y; s.z += v.z; s.w += v.w;
  }
  const float4 pb = *(const float4*)&param_b[k4];
  s.x += pb.x; s.y += pb.y; s.z += pb.z; s.w += pb.w;
  if (k4 < 32){
    bf16 o[4] = {f2b(s.x), f2b(s.y), f2b(s.z), f2b(s.w)};
    *(ushort4*)&xdbb[(size_t)m*64 + k4] = *(const ushort4*)o;
  } else {
    bf16 o[4] = {};
    *(ushort4*)&xdbb[(size_t)m*64 + k4] = *(const ushort4*)o;  // K pad
    *(float4*)&bcg[(size_t)m*32 + (k4 - 32)] = s;
  }
}

// ---------------- MFMA GEMM: C[m,n] = epi( sum_k A[m,k]*B[n,k] + bias[n] ) -------------
#define TBK 64

template<int EPI, int CONV, int NFRAG>
__launch_bounds__(256)
__global__ void mfma_gemm(const bf16* __restrict__ A, int lda,
                          const bf16* __restrict__ B, int ldb,
                          const float* __restrict__ bias,
                          float* __restrict__ outF,
                          bf16* __restrict__ outB0,
                          int ldo, int K, int azs, int ozs, int kzs)
{
  __shared__ bf16 As[128*TBK];           // 16 KB
  __shared__ bf16 Bs[32*NFRAG*TBK];      // 4/8 KB
  const int tid  = threadIdx.x;
  const int lane = tid & 63;
  const int wave = tid >> 6;
  const int wr = (wave >> 1) * 64;
  const int wc = (wave & 1) * 16 * NFRAG;
  const int mBase = blockIdx.x * 128;
  const int nBase = blockIdx.y * (32*NFRAG);
  A += (size_t)blockIdx.z * azs;
  const int nOff = blockIdx.z * ozs;
  const int koff = blockIdx.z * kzs;

  f32x4 acc[4][NFRAG] = {};

  for (int k0 = 0; k0 < K; k0 += TBK) {
    __syncthreads();
    #pragma unroll
    for (int it = 0; it < 4; it++) {      // As: 1024 chunks of 16B
      const int idx = it*256 + tid;
      const int r = idx >> 3, c16 = idx & 7;
      const bf16* ga;
      if (CONV) {
        const int tap = k0 >> 9, kk = k0 & 511;
        const int m = mBase + r;
        const int cc = m >> 8;
        int p = (m & 255) + tap - 2;
        p = min(max(p, 0), PP-1);
        ga = A + ((size_t)(cc*PP + p))*DMH + kk + c16*8;
      } else {
        ga = A + (size_t)(mBase + r)*lda + koff + k0 + c16*8;
      }
      g2l16(ga, &As[(size_t)idx*8]);
    }
    #pragma unroll
    for (int it = 0; it < NFRAG; it++) {  // Bs: 256*NFRAG chunks of 16B
      const int idx = it*256 + tid;
      const int r = idx >> 3, c16 = idx & 7;
      const bf16* gb = B + (size_t)(nBase + r)*ldb + koff + k0 + c16*8;
      g2l16(gb, &Bs[(size_t)idx*8]);
    }
    __syncthreads();
    #pragma unroll
    for (int ks = 0; ks < 2; ks++) {
      bf16x8 af[4], bfr[NFRAG];
      #pragma unroll
      for (int r = 0; r < 4; r++)
        af[r] = *(const bf16x8*)&As[(wr + r*16 + (lane & 15))*TBK + ks*32 + (lane>>4)*8];
      #pragma unroll
      for (int c = 0; c < NFRAG; c++)
        bfr[c] = *(const bf16x8*)&Bs[(wc + c*16 + (lane & 15))*TBK + ks*32 + (lane>>4)*8];
      #pragma unroll
      for (int r = 0; r < 4; r++)
        #pragma unroll
        for (int c = 0; c < NFRAG; c++)
          acc[r][c] = __builtin_amdgcn_mfma_f32_16x16x32_bf16(af[r], bfr[c], acc[r][c], 0, 0, 0);
    }
  }

  const int col0 = lane & 15;
  const int row0 = (lane >> 4) * 4;
  #pragma unroll
  for (int r = 0; r < 4; r++) {
    #pragma unroll
    for (int c = 0; c < NFRAG; c++) {
      #pragma unroll
      for (int reg = 0; reg < 4; reg++) {
        const int m = mBase + wr + r*16 + row0 + reg;
        const int n = nBase + wc + c*16 + col0;
        const float av = acc[r][c][reg];
        if (EPI == 0) {
          outF[(size_t)m*ldo + n] = av + bias[n];
        } else if (EPI == 1) {
          outB0[(size_t)m*ldo + n] = f2b(geluf(av + bias[n]));
        } else if (EPI == 2) {
          outB0[(size_t)m*ldo + n] = f2b(geluf(geluf(av + bias[n])));
        } else if (EPI == 3) {
          outB0[(size_t)m*ldo + n + nOff] = f2b(av);
        } else if (EPI == 5) {
          // dt = softplus(av + dt_b[n]); pack {dt, dt*xi} as bf16 pair -> uint plane
          const float dtv = softplusf(av + bias[n]);
          const ushort ux = ((const ushort*)outF)[(size_t)m*DIH + n];  // xi bits
          bf16 xh; *(ushort*)&xh = ux;
          bf16 dA = f2b(dtv);
          bf16 dB = f2b(dtv * b2f(xh));
          const uint pk = (uint)(*(const ushort*)&dA) | ((uint)(*(const ushort*)&dB) << 16);
          ((uint*)outB0)[(size_t)m*ldo + n] = pk;
        } else if (EPI == 6) {
          outF[(size_t)m*ldo + n + nOff] = av;       // split-K plane write (no atomics)
        }
      }
    }
  }
}

// ---------------- fused scan v5: 2 states/lane, 2 units per 256-block -----------------
// Unit = one (dg, c): 128 threads, lane (dl=ut>>3, ng=ut&7) holds states n=2ng,2ng+1
// of channel d0+dl as float2. y-reduce: in-lane fma pair + 3-stage row_shr prefix over
// the 8-lane group (clean group sums at lanes 7/15). One barrier per 16-row tile;
// triple-buffered staging, double-buffered ybF (v4-verified schedule).
__launch_bounds__(256)
__global__ void scan_v5(const float* __restrict__ bcg, const bf16* __restrict__ xi,
                        const bf16* __restrict__ gz, const uint* __restrict__ pxg,
                        const float* __restrict__ A_log, const float* __restrict__ Dp,
                        const float* __restrict__ s0,
                        bf16* __restrict__ ypre, float* __restrict__ state_out)
{
  const int dg = blockIdx.x;
  const int tid = threadIdx.x;
  const int u = tid >> 7, ut = tid & 127;
  const int c = blockIdx.y*2 + u;
  const int dl = ut >> 3, ng = ut & 7;
  const int d0 = dg*16;
  const int d  = d0 + dl;
  const int base_m = c*PP;

  __shared__ float  bcT[2][3][16][36];   // B 0..15 | C 16..31, pitch 144B
  __shared__ uint   pxT[2][3][16][20];   // packed {dt(lo), dt*xi(hi)}, pitch 80B
  __shared__ ushort xgT[2][3][16][40];   // xi 0..15 | gz 16..31, pitch 80B
  __shared__ float  ybF[2][2][16][17];
  __shared__ ushort outT[2][16][24];     // pitch 48B
  __shared__ float  DvT[2][16];

  if (ut < 16) DvT[u][ut] = Dp[d0 + ut];
  const float2 al = *(const float2*)&A_log[(size_t)d*NST + 2*ng];
  const float a20 = -__expf(al.x)*LOG2E;
  const float a21 = -__expf(al.y)*LOG2E;
  float2 s = *(const float2*)&s0[((size_t)c*DIH + d)*NST + 2*ng];

  // staging roles: every thread 1 bcg float4 + 1 secondary uint4
  const int br = ut >> 3, bc4 = (ut & 7)*4;
  float4 bc_r; uint4 sec_r;

#define STAGE_LOAD(mm) do { \
    bc_r = *(const float4*)&bcg[(size_t)((mm) + br)*32 + bc4]; \
    if (ut < 64)      sec_r = *(const uint4*)&pxg[(size_t)((mm) + (ut>>2))*DIH + d0 + (ut&3)*4]; \
    else if (ut < 96) sec_r = *(const uint4*)&((const ushort*)xi)[(size_t)((mm) + ((ut-64)>>1))*DIH + d0 + ((ut-64)&1)*8]; \
    else              sec_r = *(const uint4*)&((const ushort*)gz)[(size_t)((mm) + ((ut-96)>>1))*DIH + d0 + ((ut-96)&1)*8]; \
  } while(0)
#define STAGE_COMMIT(nbuf) do { \
    *(float4*)&bcT[u][nbuf][br][bc4] = bc_r; \
    if (ut < 64)      *(uint4*)&pxT[u][nbuf][ut>>2][(ut&3)*4] = sec_r; \
    else if (ut < 96) *(uint4*)&xgT[u][nbuf][(ut-64)>>1][((ut-64)&1)*8] = sec_r; \
    else              *(uint4*)&xgT[u][nbuf][(ut-96)>>1][16 + ((ut-96)&1)*8] = sec_r; \
  } while(0)

  STAGE_LOAD(base_m);
  STAGE_COMMIT(0);
  __syncthreads();

  for (int g = 0; g < 16; ++g){
    const int buf = g % 3, nb = (g+1) % 3, yb = g & 1;
    const int m0 = base_m + g*16;
    if (g < 15) STAGE_LOAD(m0 + 16);
    // 16-step scan, 2 states/lane
    #pragma unroll
    for (int j = 0; j < 16; j++){
      const uint pk = pxT[u][buf][j][dl];
      const float dtv  = __int_as_float(pk << 16);
      const float dtxi = __int_as_float(pk & 0xffff0000u);
      const float2 Bv = *(const float2*)&bcT[u][buf][j][2*ng];
      const float2 Cv = *(const float2*)&bcT[u][buf][j][16 + 2*ng];
      s.x = s.x*exp2f(dtv*a20) + dtxi*Bv.x;
      s.y = s.y*exp2f(dtv*a21) + dtxi*Bv.y;
      float y = fmaf(s.y, Cv.y, s.x*Cv.x);
      int t;
      t = __builtin_amdgcn_update_dpp(0, __float_as_int(y), 0x111, 0xf, 0xf, true);
      y += __int_as_float(t);
      t = __builtin_amdgcn_update_dpp(0, __float_as_int(y), 0x112, 0xf, 0xf, true);
      y += __int_as_float(t);
      t = __builtin_amdgcn_update_dpp(0, __float_as_int(y), 0x114, 0xf, 0xf, true);
      y += __int_as_float(t);
      if (ng == 7) ybF[u][yb][j][dl] = y;     // clean 8-lane group sum at lane 7/15
    }
    if (g < 15) STAGE_COMMIT(nb);
    __syncthreads();
    // epilogue: thread (ej=ut>>3, eg=ut&7) -> outputs (m0+ej, d0+2eg..2eg+1)
    {
      const int ej = ut >> 3, eg = ut & 7;
      #pragma unroll
      for (int q = 0; q < 2; q++){
        const int ed = 2*eg + q;
        bf16 xh; *(ushort*)&xh = xgT[u][buf][ej][ed];
        bf16 gh; *(ushort*)&gh = xgT[u][buf][ej][16+ed];
        bf16 hv = f2b((ybF[u][yb][ej][ed] + DvT[u][ed]*b2f(xh)) * b2f(gh));
        outT[u][ej][ed] = *(const ushort*)&hv;
      }
      if (eg < 2)
        *(uint4*)((ushort*)ypre + (size_t)(m0+ej)*DIH + d0 + eg*8) = *(const uint4*)&outT[u][ej][eg*8];
    }
  }
  *(float2*)&state_out[((size_t)c*DIH + d)*NST + 2*ng] = s;
#undef STAGE_LOAD
#undef STAGE_COMMIT
}

extern "C" void kernel_launch(void* const* d_in, const int* in_sizes, int n_in,
                              void* d_out, int out_size, void* d_ws, size_t ws_size,
                              hipStream_t stream) {
  const float* x       = (const float*)d_in[0];
  const float* s0      = (const float*)d_in[1];
  const float* in_w    = (const float*)d_in[2];
  const float* in_b    = (const float*)d_in[3];
  const float* conv_w  = (const float*)d_in[4];
  const float* conv_b  = (const float*)d_in[5];
  const float* param_w = (const float*)d_in[6];
  const float* param_b = (const float*)d_in[7];
  const float* dt_w    = (const float*)d_in[8];
  const float* dt_b    = (const float*)d_in[9];
  const float* out_w   = (const float*)d_in[10];
  const float* out_b   = (const float*)d_in[11];
  const float* A_log   = (const float*)d_in[12];
  const float* Dp      = (const float*)d_in[13];

  char* ws = (char*)d_ws;
  bf16*   xi    = (bf16*)ws;   ws += (size_t)MM*DIH*2;     //  8 MB
  bf16*   gz    = (bf16*)ws;   ws += (size_t)MM*DIH*2;     //  8 MB
  float*  bcg   = (float*)ws;  ws += (size_t)MM*32*4;      // 0.5 MB (B|C fp32)
  bf16*   xdbb  = (bf16*)ws;   ws += (size_t)MM*64*2;      // 0.5 MB (dt GEMM A)
  float*  cb2   = (float*)ws;  ws += 4096;                 //  4 KB
  bf16*   ypre  = (bf16*)ws;   ws += (size_t)MM*DIH*2;     //  8 MB
  bf16*   outwb = (bf16*)ws;   ws += (size_t)DMH*DIH*2;    //  1 MB
  bf16*   pwb   = (bf16*)ws;   ws += (size_t)64*DIH*2;     // 128 KB
  bf16*   dtwb  = (bf16*)ws;   ws += (size_t)DIH*64*2;     // 128 KB
  char*   U     = ws;          ws += (size_t)32*1024*1024; // union region, 32 MB
  // early tenants of U:
  bf16* Wfb  = (bf16*)(U);                                 // dead after conv GEMM
  bf16* xbf  = (bf16*)(U + (size_t) 4*1024*1024);          // dead after conv GEMM
  bf16* inwz = (bf16*)(U + (size_t) 8*1024*1024);
  bf16* inwT = (bf16*)(U + (size_t) 9*1024*1024);
  bf16* cwT  = (bf16*)(U + (size_t)10*1024*1024);          // dead after fold GEMM
  // late tenants of U:
  float* pxz = (float*)(U);                                // 8 MB split-K planes
  uint*  pxg = (uint*)(U + (size_t)16*1024*1024);          // 16 MB packed {dt, dt*xi}

  float* y_out  = (float*)d_out;                           // [C,P,DM] fp32
  float* st_out = y_out + (size_t)MM*DMH;                  // [C,DI,16] fp32

  hipMemsetAsync(cb2, 0, DIH*sizeof(float), stream);
  // fused prep (casts, conv repack + folded cb2, transpose, dt_w cast)
  prep_all<<<7424, 256, 0, stream>>>(x, in_w, out_w, param_w, conv_w, dt_w,
                                     in_b, conv_b, cb2,
                                     xbf, inwz, outwb, pwb, cwT, inwT, dtwb);

  // fold: Wf[k][o][m] = sum_i conv_w[o,i,k]*in_w[i,m]   (4 taps via grid.z)
  mfma_gemm<3,0,2><<<dim3(DIH/128, DMH/64, 4), 256, 0, stream>>>(
      cwT, DIH, inwT, DIH, nullptr, nullptr, Wfb, 4*DMH, DIH, DIH*DIH, DMH, 0);
  // z-half in_proj: gelu(gelu(x @ in_w_z^T + b_z)) -> gz (contiguous bf16)
  mfma_gemm<2,0,2><<<dim3(MM/128, DIH/64), 256, 0, stream>>>(
      xbf, DMH, inwz, DMH, in_b + DIH, nullptr, gz, DIH, DMH, 0, 0, 0);
  // fused conv: gelu( sum_tap x[clamp] @ Wf_tap^T + cb2 ) -> xi (contiguous bf16)
  mfma_gemm<1,1,2><<<dim3(MM/128, DIH/64), 256, 0, stream>>>(
      xbf, DMH, Wfb, 4*DMH, cb2, nullptr, xi, DIH, 4*DMH, 0, 0, 0);
  // x_db = xi @ param_w.T (split-K=8, per-z plane writes; bias added in reduce)
  mfma_gemm<6,0,2><<<dim3(MM/128, 1, 8), 256, 0, stream>>>(
      xi, DIH, pwb, DIH, nullptr, pxz, nullptr, 64, 128, 0, MM*64, 128);
  // reduce planes + param_b -> xdbb (bf16 dt input, K=64 pad) + bcg (fp32 B|C)
  reduce_cast<<<256, 256, 0, stream>>>(pxz, param_b, bcg, xdbb);
  // pxg[m][d] = pack{ softplus(dt_in @ dt_w^T + dt_b), dt * xi }  via MFMA
  mfma_gemm<5,0,2><<<dim3(MM/128, DIH/64), 256, 0, stream>>>(
      xdbb, 64, dtwb, 64, dt_b, (float*)xi, (bf16*)pxg, DIH, 64, 0, 0, 0);
  // fused scan, 2 states/lane, 2 units/block
  scan_v5<<<dim3(64, CC/2), 256, 0, stream>>>(bcg, xi, gz, pxg, A_log, Dp,
                                              s0, ypre, st_out);
  // out projection
  mfma_gemm<0,0,1><<<dim3(MM/128, DMH/32), 256, 0, stream>>>(
      ypre, DIH, outwb, DIH, out_b, y_out, nullptr, DMH, DIH, 0, 0, 0);
}

// Round 6
// 246.748 us; speedup vs baseline: 1.3162x; 1.0647x over previous
//
#include <hip/hip_runtime.h>
#include <hip/hip_bf16.h>

typedef __hip_bfloat16 bf16;
typedef short bf16x8 __attribute__((ext_vector_type(8)));
typedef float f32x4 __attribute__((ext_vector_type(4)));

#define CC 16
#define PP 256
#define DMH 512
#define DIH 1024
#define MM (CC*PP)   /* 4096 rows (c,p) */
#define NST 16
#define NDT 32
#define LOG2E 1.44269504088896f

__device__ __forceinline__ float b2f(bf16 v){ return __bfloat162float(v); }
__device__ __forceinline__ bf16  f2b(float v){ return __float2bfloat16(v); }

// fast tanh-gelu: tanh(u) = 1 - 2/(exp(2u)+1); exact limits at +-inf
__device__ __forceinline__ float geluf(float x){
  const float u = x*(0.7978845608028654f + 0.035677408136300125f*x*x);
  const float e = exp2f(2.885390081777927f*u);            // exp(2u)
  const float t = 1.0f - 2.0f*__builtin_amdgcn_rcpf(e + 1.0f);
  return 0.5f*x*(1.0f + t);
}
__device__ __forceinline__ float softplusf(float x){
  if (x > 20.0f) return x;
  return log1pf(expf(x));
}

__device__ __forceinline__ void g2l16(const bf16* g, bf16* l){
  __builtin_amdgcn_global_load_lds(
      (const __attribute__((address_space(1))) void*)g,
      (__attribute__((address_space(3))) void*)(uint32_t)(uintptr_t)l,
      16, 0, 0);
}

// ---------------- fused prep: casts + conv repack (+cb2 fold) + transpose + dtw cast --
__global__ void prep_all(const float* __restrict__ x, const float* __restrict__ in_w,
                         const float* __restrict__ out_w, const float* __restrict__ param_w,
                         const float* __restrict__ conv_w, const float* __restrict__ dt_w,
                         const float* __restrict__ in_b, const float* __restrict__ conv_b,
                         float* __restrict__ cb2,
                         bf16* __restrict__ xbf, bf16* __restrict__ inwz,
                         bf16* __restrict__ outwb, bf16* __restrict__ pwb,
                         bf16* __restrict__ cwT, bf16* __restrict__ inwT,
                         bf16* __restrict__ dtwb)
{
  const int b = blockIdx.x, tid = threadIdx.x;
  if (b < 3136){
    const float* src; bf16* dst; int i;
    if (b < 2048)      { src = x;                       dst = xbf;   i = b*256 + tid; }
    else if (b < 2560) { src = in_w + (size_t)DIH*DMH;  dst = inwz;  i = (b-2048)*256 + tid; }
    else if (b < 3072) { src = out_w;                   dst = outwb; i = (b-2560)*256 + tid; }
    else               { src = param_w;                 dst = pwb;   i = (b-3072)*256 + tid; }
    float4 v = ((const float4*)src)[i];
    bf16 o[4] = {f2b(v.x), f2b(v.y), f2b(v.z), f2b(v.w)};
    *(ushort4*)&dst[(size_t)i*4] = *(const ushort4*)o;
  } else if (b < 7232){
    const size_t idx = (size_t)(b-3136)*256 + tid;      // o*1024 + i
    const float4 v = *(const float4*)(conv_w + idx*4);  // [o][i][tap] -> [tap][o][i]
    cwT[idx]                     = f2b(v.x);
    cwT[(size_t)DIH*DIH   + idx] = f2b(v.y);
    cwT[(size_t)2*DIH*DIH + idx] = f2b(v.z);
    cwT[(size_t)3*DIH*DIH + idx] = f2b(v.w);
    // folded bias partial: cb2[o] += sum_i (sum_k w[o,i,k]) * in_b[i]
    __shared__ float ls[4];
    const int i = (int)(idx & 1023);
    float acc = (v.x + v.y + v.z + v.w) * in_b[i];
    for (int off = 32; off; off >>= 1) acc += __shfl_down(acc, off);
    if ((tid & 63) == 0) ls[tid >> 6] = acc;
    __syncthreads();
    if (tid == 0){
      const int o = (int)(idx >> 10);
      float tot = ls[0] + ls[1] + ls[2] + ls[3];
      if (((b - 3136) & 3) == 0) tot += conv_b[o];
      atomicAdd(&cb2[o], tot);
    }
  } else if (b < 7360){
    // in_w xi-half [i<1024][m<512] -> inwT [m][i], 64x64 LDS tile
    __shared__ float T[64][65];
    const int b2 = b - 7232;
    const int i0 = (b2 >> 3)*64, m0 = (b2 & 7)*64;
    const int r = tid >> 2, c0 = (tid & 3)*16;
    #pragma unroll
    for (int t = 0; t < 4; t++){
      float4 v = *(const float4*)&in_w[(size_t)(i0 + r)*DMH + m0 + c0 + t*4];
      T[r][c0+t*4+0] = v.x; T[r][c0+t*4+1] = v.y;
      T[r][c0+t*4+2] = v.z; T[r][c0+t*4+3] = v.w;
    }
    __syncthreads();
    bf16 o[16];
    #pragma unroll
    for (int t = 0; t < 16; t++) o[t] = f2b(T[c0 + t][r]);
    *(ushort4*)&inwT[(size_t)(m0 + r)*DIH + i0 + c0]      = *(const ushort4*)&o[0];
    *(ushort4*)&inwT[(size_t)(m0 + r)*DIH + i0 + c0 + 4]  = *(const ushort4*)&o[4];
    *(ushort4*)&inwT[(size_t)(m0 + r)*DIH + i0 + c0 + 8]  = *(const ushort4*)&o[8];
    *(ushort4*)&inwT[(size_t)(m0 + r)*DIH + i0 + c0 + 12] = *(const ushort4*)&o[12];
  } else {
    // dt_w [1024][32] fp32 -> dtwb [1024][64] bf16, cols 32..63 zero (K=64 pad)
    const int idx4 = (b-7360)*256 + tid;          // 0..16383
    const int d = idx4 >> 4, k4 = (idx4 & 15)*4;
    bf16 o[4] = {};
    if (k4 < 32){
      const float4 v = *(const float4*)&dt_w[(size_t)d*NDT + k4];
      o[0]=f2b(v.x); o[1]=f2b(v.y); o[2]=f2b(v.z); o[3]=f2b(v.w);
    }
    *(ushort4*)&dtwb[(size_t)d*64 + k4] = *(const ushort4*)o;
  }
}

// reduce 8 split-K planes + param_b -> xdbb (bf16 cols 0..31, K=64 pad) + bcg (fp32 B|C)
__global__ void reduce_cast(const float* __restrict__ pxz, const float* __restrict__ param_b,
                            float* __restrict__ bcg, bf16* __restrict__ xdbb){
  const int idx = blockIdx.x*256 + threadIdx.x;   // 0..65535 float4 units
  const int m = idx >> 4, k4 = (idx & 15)*4;
  float4 s = make_float4(0.f,0.f,0.f,0.f);
  #pragma unroll
  for (int z = 0; z < 8; z++){
    const float4 v = *(const float4*)&pxz[(size_t)z*MM*64 + (size_t)m*64 + k4];
    s.x += v.x; s.y += v.y; s.z += v.z; s.w += v.w;
  }
  const float4 pb = *(const float4*)&param_b[k4];
  s.x += pb.x; s.y += pb.y; s.z += pb.z; s.w += pb.w;
  if (k4 < 32){
    bf16 o[4] = {f2b(s.x), f2b(s.y), f2b(s.z), f2b(s.w)};
    *(ushort4*)&xdbb[(size_t)m*64 + k4] = *(const ushort4*)o;
  } else {
    bf16 o[4] = {};
    *(ushort4*)&xdbb[(size_t)m*64 + k4] = *(const ushort4*)o;  // K pad
    *(float4*)&bcg[(size_t)m*32 + (k4 - 32)] = s;
  }
}

// ---------------- MFMA GEMM: C[m,n] = epi( sum_k A[m,k]*B[n,k] + bias[n] ) -------------
// LDS XOR-swizzle (T2, gload_lds-compatible): LDS dest stays LINEAR; the global
// SOURCE chunk is pre-swizzled (c16 ^ (row&7)) and the MFMA-side ds_read applies
// the same XOR. 16 lanes reading 16 rows then span 8 chunk slots (2-way = free)
// instead of one bank (16-way).
#define TBK 64

template<int EPI, int CONV, int NFRAG>
__launch_bounds__(256)
__global__ void mfma_gemm(const bf16* __restrict__ A, int lda,
                          const bf16* __restrict__ B, int ldb,
                          const float* __restrict__ bias,
                          float* __restrict__ outF,
                          bf16* __restrict__ outB0,
                          int ldo, int K, int azs, int ozs, int kzs)
{
  __shared__ bf16 As[128*TBK];           // 16 KB
  __shared__ bf16 Bs[32*NFRAG*TBK];      // 4/8 KB
  const int tid  = threadIdx.x;
  const int lane = tid & 63;
  const int wave = tid >> 6;
  const int wr = (wave >> 1) * 64;
  const int wc = (wave & 1) * 16 * NFRAG;
  const int mBase = blockIdx.x * 128;
  const int nBase = blockIdx.y * (32*NFRAG);
  A += (size_t)blockIdx.z * azs;
  const int nOff = blockIdx.z * ozs;
  const int koff = blockIdx.z * kzs;

  f32x4 acc[4][NFRAG] = {};

  for (int k0 = 0; k0 < K; k0 += TBK) {
    __syncthreads();
    #pragma unroll
    for (int it = 0; it < 4; it++) {      // As: 1024 chunks of 16B
      const int idx = it*256 + tid;
      const int r = idx >> 3;
      const int cs = (idx & 7) ^ (r & 7);         // pre-swizzled source chunk
      const bf16* ga;
      if (CONV) {
        const int tap = k0 >> 9, kk = k0 & 511;
        const int m = mBase + r;
        const int cc = m >> 8;
        int p = (m & 255) + tap - 2;
        p = min(max(p, 0), PP-1);
        ga = A + ((size_t)(cc*PP + p))*DMH + kk + cs*8;
      } else {
        ga = A + (size_t)(mBase + r)*lda + koff + k0 + cs*8;
      }
      g2l16(ga, &As[(size_t)idx*8]);
    }
    #pragma unroll
    for (int it = 0; it < NFRAG; it++) {  // Bs: 256*NFRAG chunks of 16B
      const int idx = it*256 + tid;
      const int r = idx >> 3;
      const int cs = (idx & 7) ^ (r & 7);
      const bf16* gb = B + (size_t)(nBase + r)*ldb + koff + k0 + cs*8;
      g2l16(gb, &Bs[(size_t)idx*8]);
    }
    __syncthreads();
    #pragma unroll
    for (int ks = 0; ks < 2; ks++) {
      bf16x8 af[4], bfr[NFRAG];
      #pragma unroll
      for (int r = 0; r < 4; r++){
        const int rr = wr + r*16 + (lane & 15);
        const int ch = (ks*4 + (lane>>4)) ^ (rr & 7);
        af[r] = *(const bf16x8*)&As[rr*TBK + ch*8];
      }
      #pragma unroll
      for (int c = 0; c < NFRAG; c++){
        const int rn = wc + c*16 + (lane & 15);
        const int ch = (ks*4 + (lane>>4)) ^ (rn & 7);
        bfr[c] = *(const bf16x8*)&Bs[rn*TBK + ch*8];
      }
      #pragma unroll
      for (int r = 0; r < 4; r++)
        #pragma unroll
        for (int c = 0; c < NFRAG; c++)
          acc[r][c] = __builtin_amdgcn_mfma_f32_16x16x32_bf16(af[r], bfr[c], acc[r][c], 0, 0, 0);
    }
  }

  const int col0 = lane & 15;
  const int row0 = (lane >> 4) * 4;
  #pragma unroll
  for (int r = 0; r < 4; r++) {
    #pragma unroll
    for (int c = 0; c < NFRAG; c++) {
      #pragma unroll
      for (int reg = 0; reg < 4; reg++) {
        const int m = mBase + wr + r*16 + row0 + reg;
        const int n = nBase + wc + c*16 + col0;
        const float av = acc[r][c][reg];
        if (EPI == 0) {
          outF[(size_t)m*ldo + n] = av + bias[n];
        } else if (EPI == 1) {
          outB0[(size_t)m*ldo + n] = f2b(geluf(av + bias[n]));
        } else if (EPI == 2) {
          outB0[(size_t)m*ldo + n] = f2b(geluf(geluf(av + bias[n])));
        } else if (EPI == 3) {
          outB0[(size_t)m*ldo + n + nOff] = f2b(av);
        } else if (EPI == 5) {
          // dt = softplus(av + dt_b[n]); pack {dt, dt*xi} as bf16 pair -> uint plane
          const float dtv = softplusf(av + bias[n]);
          const ushort ux = ((const ushort*)outF)[(size_t)m*DIH + n];  // xi bits
          bf16 xh; *(ushort*)&xh = ux;
          bf16 dA = f2b(dtv);
          bf16 dB = f2b(dtv * b2f(xh));
          const uint pk = (uint)(*(const ushort*)&dA) | ((uint)(*(const ushort*)&dB) << 16);
          ((uint*)outB0)[(size_t)m*ldo + n] = pk;
        } else if (EPI == 6) {
          outF[(size_t)m*ldo + n + nOff] = av;       // split-K plane write (no atomics)
        }
      }
    }
  }
}

// ---------------- fused scan v5: 2 states/lane, 2 units per 256-block -----------------
__launch_bounds__(256)
__global__ void scan_v5(const float* __restrict__ bcg, const bf16* __restrict__ xi,
                        const bf16* __restrict__ gz, const uint* __restrict__ pxg,
                        const float* __restrict__ A_log, const float* __restrict__ Dp,
                        const float* __restrict__ s0,
                        bf16* __restrict__ ypre, float* __restrict__ state_out)
{
  const int dg = blockIdx.x;
  const int tid = threadIdx.x;
  const int u = tid >> 7, ut = tid & 127;
  const int c = blockIdx.y*2 + u;
  const int dl = ut >> 3, ng = ut & 7;
  const int d0 = dg*16;
  const int d  = d0 + dl;
  const int base_m = c*PP;

  __shared__ float  bcT[2][3][16][36];   // B 0..15 | C 16..31, pitch 144B
  __shared__ uint   pxT[2][3][16][20];   // packed {dt(lo), dt*xi(hi)}, pitch 80B
  __shared__ ushort xgT[2][3][16][40];   // xi 0..15 | gz 16..31, pitch 80B
  __shared__ float  ybF[2][2][16][17];
  __shared__ ushort outT[2][16][24];     // pitch 48B
  __shared__ float  DvT[2][16];

  if (ut < 16) DvT[u][ut] = Dp[d0 + ut];
  const float2 al = *(const float2*)&A_log[(size_t)d*NST + 2*ng];
  const float a20 = -__expf(al.x)*LOG2E;
  const float a21 = -__expf(al.y)*LOG2E;
  float2 s = *(const float2*)&s0[((size_t)c*DIH + d)*NST + 2*ng];

  // staging roles: every thread 1 bcg float4 + 1 secondary uint4
  const int br = ut >> 3, bc4 = (ut & 7)*4;
  float4 bc_r; uint4 sec_r;

#define STAGE_LOAD(mm) do { \
    bc_r = *(const float4*)&bcg[(size_t)((mm) + br)*32 + bc4]; \
    if (ut < 64)      sec_r = *(const uint4*)&pxg[(size_t)((mm) + (ut>>2))*DIH + d0 + (ut&3)*4]; \
    else if (ut < 96) sec_r = *(const uint4*)&((const ushort*)xi)[(size_t)((mm) + ((ut-64)>>1))*DIH + d0 + ((ut-64)&1)*8]; \
    else              sec_r = *(const uint4*)&((const ushort*)gz)[(size_t)((mm) + ((ut-96)>>1))*DIH + d0 + ((ut-96)&1)*8]; \
  } while(0)
#define STAGE_COMMIT(nbuf) do { \
    *(float4*)&bcT[u][nbuf][br][bc4] = bc_r; \
    if (ut < 64)      *(uint4*)&pxT[u][nbuf][ut>>2][(ut&3)*4] = sec_r; \
    else if (ut < 96) *(uint4*)&xgT[u][nbuf][(ut-64)>>1][((ut-64)&1)*8] = sec_r; \
    else              *(uint4*)&xgT[u][nbuf][(ut-96)>>1][16 + ((ut-96)&1)*8] = sec_r; \
  } while(0)

  STAGE_LOAD(base_m);
  STAGE_COMMIT(0);
  __syncthreads();

  for (int g = 0; g < 16; ++g){
    const int buf = g % 3, nb = (g+1) % 3, yb = g & 1;
    const int m0 = base_m + g*16;
    if (g < 15) STAGE_LOAD(m0 + 16);
    // 16-step scan, 2 states/lane
    #pragma unroll
    for (int j = 0; j < 16; j++){
      const uint pk = pxT[u][buf][j][dl];
      const float dtv  = __int_as_float(pk << 16);
      const float dtxi = __int_as_float(pk & 0xffff0000u);
      const float2 Bv = *(const float2*)&bcT[u][buf][j][2*ng];
      const float2 Cv = *(const float2*)&bcT[u][buf][j][16 + 2*ng];
      s.x = s.x*exp2f(dtv*a20) + dtxi*Bv.x;
      s.y = s.y*exp2f(dtv*a21) + dtxi*Bv.y;
      float y = fmaf(s.y, Cv.y, s.x*Cv.x);
      int t;
      t = __builtin_amdgcn_update_dpp(0, __float_as_int(y), 0x111, 0xf, 0xf, true);
      y += __int_as_float(t);
      t = __builtin_amdgcn_update_dpp(0, __float_as_int(y), 0x112, 0xf, 0xf, true);
      y += __int_as_float(t);
      t = __builtin_amdgcn_update_dpp(0, __float_as_int(y), 0x114, 0xf, 0xf, true);
      y += __int_as_float(t);
      if (ng == 7) ybF[u][yb][j][dl] = y;     // clean 8-lane group sum at lane 7/15
    }
    if (g < 15) STAGE_COMMIT(nb);
    __syncthreads();
    // epilogue: thread (ej=ut>>3, eg=ut&7) -> outputs (m0+ej, d0+2eg..2eg+1)
    {
      const int ej = ut >> 3, eg = ut & 7;
      #pragma unroll
      for (int q = 0; q < 2; q++){
        const int ed = 2*eg + q;
        bf16 xh; *(ushort*)&xh = xgT[u][buf][ej][ed];
        bf16 gh; *(ushort*)&gh = xgT[u][buf][ej][16+ed];
        bf16 hv = f2b((ybF[u][yb][ej][ed] + DvT[u][ed]*b2f(xh)) * b2f(gh));
        outT[u][ej][ed] = *(const ushort*)&hv;
      }
      if (eg < 2)
        *(uint4*)((ushort*)ypre + (size_t)(m0+ej)*DIH + d0 + eg*8) = *(const uint4*)&outT[u][ej][eg*8];
    }
  }
  *(float2*)&state_out[((size_t)c*DIH + d)*NST + 2*ng] = s;
#undef STAGE_LOAD
#undef STAGE_COMMIT
}

extern "C" void kernel_launch(void* const* d_in, const int* in_sizes, int n_in,
                              void* d_out, int out_size, void* d_ws, size_t ws_size,
                              hipStream_t stream) {
  const float* x       = (const float*)d_in[0];
  const float* s0      = (const float*)d_in[1];
  const float* in_w    = (const float*)d_in[2];
  const float* in_b    = (const float*)d_in[3];
  const float* conv_w  = (const float*)d_in[4];
  const float* conv_b  = (const float*)d_in[5];
  const float* param_w = (const float*)d_in[6];
  const float* param_b = (const float*)d_in[7];
  const float* dt_w    = (const float*)d_in[8];
  const float* dt_b    = (const float*)d_in[9];
  const float* out_w   = (const float*)d_in[10];
  const float* out_b   = (const float*)d_in[11];
  const float* A_log   = (const float*)d_in[12];
  const float* Dp      = (const float*)d_in[13];

  char* ws = (char*)d_ws;
  bf16*   xi    = (bf16*)ws;   ws += (size_t)MM*DIH*2;     //  8 MB
  bf16*   gz    = (bf16*)ws;   ws += (size_t)MM*DIH*2;     //  8 MB
  float*  bcg   = (float*)ws;  ws += (size_t)MM*32*4;      // 0.5 MB (B|C fp32)
  bf16*   xdbb  = (bf16*)ws;   ws += (size_t)MM*64*2;      // 0.5 MB (dt GEMM A)
  float*  cb2   = (float*)ws;  ws += 4096;                 //  4 KB
  bf16*   ypre  = (bf16*)ws;   ws += (size_t)MM*DIH*2;     //  8 MB
  bf16*   outwb = (bf16*)ws;   ws += (size_t)DMH*DIH*2;    //  1 MB
  bf16*   pwb   = (bf16*)ws;   ws += (size_t)64*DIH*2;     // 128 KB
  bf16*   dtwb  = (bf16*)ws;   ws += (size_t)DIH*64*2;     // 128 KB
  char*   U     = ws;          ws += (size_t)32*1024*1024; // union region, 32 MB
  // early tenants of U:
  bf16* Wfb  = (bf16*)(U);                                 // dead after conv GEMM
  bf16* xbf  = (bf16*)(U + (size_t) 4*1024*1024);          // dead after conv GEMM
  bf16* inwz = (bf16*)(U + (size_t) 8*1024*1024);
  bf16* inwT = (bf16*)(U + (size_t) 9*1024*1024);
  bf16* cwT  = (bf16*)(U + (size_t)10*1024*1024);          // dead after fold GEMM
  // late tenants of U:
  float* pxz = (float*)(U);                                // 8 MB split-K planes
  uint*  pxg = (uint*)(U + (size_t)16*1024*1024);          // 16 MB packed {dt, dt*xi}

  float* y_out  = (float*)d_out;                           // [C,P,DM] fp32
  float* st_out = y_out + (size_t)MM*DMH;                  // [C,DI,16] fp32

  hipMemsetAsync(cb2, 0, DIH*sizeof(float), stream);
  // fused prep (casts, conv repack + folded cb2, transpose, dt_w cast)
  prep_all<<<7424, 256, 0, stream>>>(x, in_w, out_w, param_w, conv_w, dt_w,
                                     in_b, conv_b, cb2,
                                     xbf, inwz, outwb, pwb, cwT, inwT, dtwb);

  // fold: Wf[k][o][m] = sum_i conv_w[o,i,k]*in_w[i,m]   (4 taps via grid.z)
  mfma_gemm<3,0,1><<<dim3(DIH/128, DMH/32, 4), 256, 0, stream>>>(
      cwT, DIH, inwT, DIH, nullptr, nullptr, Wfb, 4*DMH, DIH, DIH*DIH, DMH, 0);
  // z-half in_proj: gelu(gelu(x @ in_w_z^T + b_z)) -> gz (contiguous bf16)
  mfma_gemm<2,0,1><<<dim3(MM/128, DIH/32), 256, 0, stream>>>(
      xbf, DMH, inwz, DMH, in_b + DIH, nullptr, gz, DIH, DMH, 0, 0, 0);
  // fused conv: gelu( sum_tap x[clamp] @ Wf_tap^T + cb2 ) -> xi (contiguous bf16)
  mfma_gemm<1,1,1><<<dim3(MM/128, DIH/32), 256, 0, stream>>>(
      xbf, DMH, Wfb, 4*DMH, cb2, nullptr, xi, DIH, 4*DMH, 0, 0, 0);
  // x_db = xi @ param_w.T (split-K=8, per-z plane writes; bias added in reduce)
  mfma_gemm<6,0,1><<<dim3(MM/128, 2, 8), 256, 0, stream>>>(
      xi, DIH, pwb, DIH, nullptr, pxz, nullptr, 64, 128, 0, MM*64, 128);
  // reduce planes + param_b -> xdbb (bf16 dt input, K=64 pad) + bcg (fp32 B|C)
  reduce_cast<<<256, 256, 0, stream>>>(pxz, param_b, bcg, xdbb);
  // pxg[m][d] = pack{ softplus(dt_in @ dt_w^T + dt_b), dt * xi }  via MFMA
  mfma_gemm<5,0,1><<<dim3(MM/128, DIH/32), 256, 0, stream>>>(
      xdbb, 64, dtwb, 64, dt_b, (float*)xi, (bf16*)pxg, DIH, 64, 0, 0, 0);
  // fused scan, 2 states/lane, 2 units/block
  scan_v5<<<dim3(64, CC/2), 256, 0, stream>>>(bcg, xi, gz, pxg, A_log, Dp,
                                              s0, ypre, st_out);
  // out projection
  mfma_gemm<0,0,1><<<dim3(MM/128, DMH/32), 256, 0, stream>>>(
      ypre, DIH, outwb, DIH, out_b, y_out, nullptr, DMH, DIH, 0, 0, 0);
}

// Round 7
// 224.644 us; speedup vs baseline: 1.4457x; 1.0984x over previous
//
#include <hip/hip_runtime.h>
#include <hip/hip_bf16.h>

typedef __hip_bfloat16 bf16;
typedef short bf16x8 __attribute__((ext_vector_type(8)));
typedef float f32x4 __attribute__((ext_vector_type(4)));

#define CC 16
#define PP 256
#define DMH 512
#define DIH 1024
#define MM (CC*PP)   /* 4096 rows (c,p) */
#define NST 16
#define NDT 32
#define LOG2E 1.44269504088896f

__device__ __forceinline__ float b2f(bf16 v){ return __bfloat162float(v); }
__device__ __forceinline__ bf16  f2b(float v){ return __float2bfloat16(v); }

// fast tanh-gelu: tanh(u) = 1 - 2/(exp(2u)+1); exact limits at +-inf
__device__ __forceinline__ float geluf(float x){
  const float u = x*(0.7978845608028654f + 0.035677408136300125f*x*x);
  const float e = __builtin_amdgcn_exp2f(2.885390081777927f*u);   // exp(2u)
  const float t = 1.0f - 2.0f*__builtin_amdgcn_rcpf(e + 1.0f);
  return 0.5f*x*(1.0f + t);
}
// softplus via v_exp/v_log: ln(1+e^x) = ln2 * log2(1 + exp2(x*log2e))
__device__ __forceinline__ float softplusf(float x){
  if (x > 20.0f) return x;
  const float e = __builtin_amdgcn_exp2f(x * LOG2E);
  return 0.6931471805599453f * __builtin_amdgcn_logf(1.0f + e);
}

__device__ __forceinline__ void g2l16(const bf16* g, bf16* l){
  __builtin_amdgcn_global_load_lds(
      (const __attribute__((address_space(1))) void*)g,
      (__attribute__((address_space(3))) void*)(uint32_t)(uintptr_t)l,
      16, 0, 0);
}

// ---------------- fused prep: casts + conv repack (+cb2 fold) + transpose + dtw cast --
__global__ void prep_all(const float* __restrict__ x, const float* __restrict__ in_w,
                         const float* __restrict__ out_w, const float* __restrict__ param_w,
                         const float* __restrict__ conv_w, const float* __restrict__ dt_w,
                         const float* __restrict__ in_b, const float* __restrict__ conv_b,
                         float* __restrict__ cb2,
                         bf16* __restrict__ xbf, bf16* __restrict__ inwz,
                         bf16* __restrict__ outwb, bf16* __restrict__ pwb,
                         bf16* __restrict__ cwT, bf16* __restrict__ inwT,
                         bf16* __restrict__ dtwb)
{
  const int b = blockIdx.x, tid = threadIdx.x;
  if (b < 3136){
    const float* src; bf16* dst; int i;
    if (b < 2048)      { src = x;                       dst = xbf;   i = b*256 + tid; }
    else if (b < 2560) { src = in_w + (size_t)DIH*DMH;  dst = inwz;  i = (b-2048)*256 + tid; }
    else if (b < 3072) { src = out_w;                   dst = outwb; i = (b-2560)*256 + tid; }
    else               { src = param_w;                 dst = pwb;   i = (b-3072)*256 + tid; }
    float4 v = ((const float4*)src)[i];
    bf16 o[4] = {f2b(v.x), f2b(v.y), f2b(v.z), f2b(v.w)};
    *(ushort4*)&dst[(size_t)i*4] = *(const ushort4*)o;
  } else if (b < 7232){
    const size_t idx = (size_t)(b-3136)*256 + tid;      // o*1024 + i
    const float4 v = *(const float4*)(conv_w + idx*4);  // [o][i][tap] -> [tap][o][i]
    cwT[idx]                     = f2b(v.x);
    cwT[(size_t)DIH*DIH   + idx] = f2b(v.y);
    cwT[(size_t)2*DIH*DIH + idx] = f2b(v.z);
    cwT[(size_t)3*DIH*DIH + idx] = f2b(v.w);
    // folded bias partial: cb2[o] += sum_i (sum_k w[o,i,k]) * in_b[i]
    __shared__ float ls[4];
    const int i = (int)(idx & 1023);
    float acc = (v.x + v.y + v.z + v.w) * in_b[i];
    for (int off = 32; off; off >>= 1) acc += __shfl_down(acc, off);
    if ((tid & 63) == 0) ls[tid >> 6] = acc;
    __syncthreads();
    if (tid == 0){
      const int o = (int)(idx >> 10);
      float tot = ls[0] + ls[1] + ls[2] + ls[3];
      if (((b - 3136) & 3) == 0) tot += conv_b[o];
      atomicAdd(&cb2[o], tot);
    }
  } else if (b < 7360){
    // in_w xi-half [i<1024][m<512] -> inwT [m][i], 64x64 LDS tile
    __shared__ float T[64][65];
    const int b2 = b - 7232;
    const int i0 = (b2 >> 3)*64, m0 = (b2 & 7)*64;
    const int r = tid >> 2, c0 = (tid & 3)*16;
    #pragma unroll
    for (int t = 0; t < 4; t++){
      float4 v = *(const float4*)&in_w[(size_t)(i0 + r)*DMH + m0 + c0 + t*4];
      T[r][c0+t*4+0] = v.x; T[r][c0+t*4+1] = v.y;
      T[r][c0+t*4+2] = v.z; T[r][c0+t*4+3] = v.w;
    }
    __syncthreads();
    bf16 o[16];
    #pragma unroll
    for (int t = 0; t < 16; t++) o[t] = f2b(T[c0 + t][r]);
    *(ushort4*)&inwT[(size_t)(m0 + r)*DIH + i0 + c0]      = *(const ushort4*)&o[0];
    *(ushort4*)&inwT[(size_t)(m0 + r)*DIH + i0 + c0 + 4]  = *(const ushort4*)&o[4];
    *(ushort4*)&inwT[(size_t)(m0 + r)*DIH + i0 + c0 + 8]  = *(const ushort4*)&o[8];
    *(ushort4*)&inwT[(size_t)(m0 + r)*DIH + i0 + c0 + 12] = *(const ushort4*)&o[12];
  } else {
    // dt_w [1024][32] fp32 -> dtwb [1024][64] bf16, cols 32..63 zero (K=64 pad)
    const int idx4 = (b-7360)*256 + tid;          // 0..16383
    const int d = idx4 >> 4, k4 = (idx4 & 15)*4;
    bf16 o[4] = {};
    if (k4 < 32){
      const float4 v = *(const float4*)&dt_w[(size_t)d*NDT + k4];
      o[0]=f2b(v.x); o[1]=f2b(v.y); o[2]=f2b(v.z); o[3]=f2b(v.w);
    }
    *(ushort4*)&dtwb[(size_t)d*64 + k4] = *(const ushort4*)o;
  }
}

// reduce 8 split-K planes + param_b -> xdbb (bf16 cols 0..31, K=64 pad) + bcg (fp32 B|C)
__global__ void reduce_cast(const float* __restrict__ pxz, const float* __restrict__ param_b,
                            float* __restrict__ bcg, bf16* __restrict__ xdbb){
  const int idx = blockIdx.x*256 + threadIdx.x;   // 0..65535 float4 units
  const int m = idx >> 4, k4 = (idx & 15)*4;
  float4 s = make_float4(0.f,0.f,0.f,0.f);
  #pragma unroll
  for (int z = 0; z < 8; z++){
    const float4 v = *(const float4*)&pxz[(size_t)z*MM*64 + (size_t)m*64 + k4];
    s.x += v.x; s.y += v.y; s.z += v.z; s.w += v.w;
  }
  const float4 pb = *(const float4*)&param_b[k4];
  s.x += pb.x; s.y += pb.y; s.z += pb.z; s.w += pb.w;
  if (k4 < 32){
    bf16 o[4] = {f2b(s.x), f2b(s.y), f2b(s.z), f2b(s.w)};
    *(ushort4*)&xdbb[(size_t)m*64 + k4] = *(const ushort4*)o;
  } else {
    bf16 o[4] = {};
    *(ushort4*)&xdbb[(size_t)m*64 + k4] = *(const ushort4*)o;  // K pad
    *(float4*)&bcg[(size_t)m*32 + (k4 - 32)] = s;
  }
}

// ---------------- MFMA GEMM: C[m,n] = epi( sum_k A[m,k]*B[n,k] + bias[n] ) -------------
// LDS XOR-swizzle (T2, gload_lds-compatible): LDS dest stays LINEAR; the global
// SOURCE chunk is pre-swizzled (c16 ^ (row&7)) and the MFMA-side ds_read applies
// the same XOR. 16 lanes reading 16 rows then span 8 chunk slots (2-way = free)
// instead of one bank (16-way).
#define TBK 64

template<int EPI, int CONV, int NFRAG>
__launch_bounds__(256)
__global__ void mfma_gemm(const bf16* __restrict__ A, int lda,
                          const bf16* __restrict__ B, int ldb,
                          const float* __restrict__ bias,
                          float* __restrict__ outF,
                          bf16* __restrict__ outB0,
                          int ldo, int K, int azs, int ozs, int kzs)
{
  __shared__ bf16 As[128*TBK];           // 16 KB
  __shared__ bf16 Bs[32*NFRAG*TBK];      // 4/8 KB
  const int tid  = threadIdx.x;
  const int lane = tid & 63;
  const int wave = tid >> 6;
  const int wr = (wave >> 1) * 64;
  const int wc = (wave & 1) * 16 * NFRAG;
  const int mBase = blockIdx.x * 128;
  const int nBase = blockIdx.y * (32*NFRAG);
  A += (size_t)blockIdx.z * azs;
  const int nOff = blockIdx.z * ozs;
  const int koff = blockIdx.z * kzs;

  f32x4 acc[4][NFRAG] = {};

  for (int k0 = 0; k0 < K; k0 += TBK) {
    __syncthreads();
    #pragma unroll
    for (int it = 0; it < 4; it++) {      // As: 1024 chunks of 16B
      const int idx = it*256 + tid;
      const int r = idx >> 3;
      const int cs = (idx & 7) ^ (r & 7);         // pre-swizzled source chunk
      const bf16* ga;
      if (CONV) {
        const int tap = k0 >> 9, kk = k0 & 511;
        const int m = mBase + r;
        const int cc = m >> 8;
        int p = (m & 255) + tap - 2;
        p = min(max(p, 0), PP-1);
        ga = A + ((size_t)(cc*PP + p))*DMH + kk + cs*8;
      } else {
        ga = A + (size_t)(mBase + r)*lda + koff + k0 + cs*8;
      }
      g2l16(ga, &As[(size_t)idx*8]);
    }
    #pragma unroll
    for (int it = 0; it < NFRAG; it++) {  // Bs: 256*NFRAG chunks of 16B
      const int idx = it*256 + tid;
      const int r = idx >> 3;
      const int cs = (idx & 7) ^ (r & 7);
      const bf16* gb = B + (size_t)(nBase + r)*ldb + koff + k0 + cs*8;
      g2l16(gb, &Bs[(size_t)idx*8]);
    }
    __syncthreads();
    #pragma unroll
    for (int ks = 0; ks < 2; ks++) {
      bf16x8 af[4], bfr[NFRAG];
      #pragma unroll
      for (int r = 0; r < 4; r++){
        const int rr = wr + r*16 + (lane & 15);
        const int ch = (ks*4 + (lane>>4)) ^ (rr & 7);
        af[r] = *(const bf16x8*)&As[rr*TBK + ch*8];
      }
      #pragma unroll
      for (int c = 0; c < NFRAG; c++){
        const int rn = wc + c*16 + (lane & 15);
        const int ch = (ks*4 + (lane>>4)) ^ (rn & 7);
        bfr[c] = *(const bf16x8*)&Bs[rn*TBK + ch*8];
      }
      #pragma unroll
      for (int r = 0; r < 4; r++)
        #pragma unroll
        for (int c = 0; c < NFRAG; c++)
          acc[r][c] = __builtin_amdgcn_mfma_f32_16x16x32_bf16(af[r], bfr[c], acc[r][c], 0, 0, 0);
    }
  }

  const int col0 = lane & 15;
  const int row0 = (lane >> 4) * 4;
  #pragma unroll
  for (int r = 0; r < 4; r++) {
    #pragma unroll
    for (int c = 0; c < NFRAG; c++) {
      #pragma unroll
      for (int reg = 0; reg < 4; reg++) {
        const int m = mBase + wr + r*16 + row0 + reg;
        const int n = nBase + wc + c*16 + col0;
        const float av = acc[r][c][reg];
        if (EPI == 0) {
          outF[(size_t)m*ldo + n] = av + bias[n];
        } else if (EPI == 1) {
          outB0[(size_t)m*ldo + n] = f2b(geluf(av + bias[n]));
        } else if (EPI == 2) {
          outB0[(size_t)m*ldo + n] = f2b(geluf(geluf(av + bias[n])));
        } else if (EPI == 3) {
          outB0[(size_t)m*ldo + n + nOff] = f2b(av);
        } else if (EPI == 5) {
          // dt = softplus(av + dt_b[n]); pack {dt, dt*xi} as bf16 pair -> uint plane
          const float dtv = softplusf(av + bias[n]);
          const ushort ux = ((const ushort*)outF)[(size_t)m*DIH + n];  // xi bits
          bf16 xh; *(ushort*)&xh = ux;
          bf16 dA = f2b(dtv);
          bf16 dB = f2b(dtv * b2f(xh));
          const uint pk = (uint)(*(const ushort*)&dA) | ((uint)(*(const ushort*)&dB) << 16);
          ((uint*)outB0)[(size_t)m*ldo + n] = pk;
        } else if (EPI == 6) {
          outF[(size_t)m*ldo + n + nOff] = av;       // split-K plane write (no atomics)
        }
      }
    }
  }
}

// ---------------- fused scan v6: 2 states/lane, tile-level register batching ----------
// Per 16-row tile: one unrolled pass pulls all {pk,Bv,Cv} into registers and batches
// the 32 exp2 + B-muls (single lgkmcnt drain), then the 16-step recurrence is a pure
// fma chain (4cyc/step) with the y/DPP tree off-chain. VGPR ~190 is free: occupancy
// is grid-capped at 2 waves/SIMD (512 blocks x 4 waves).
__launch_bounds__(256, 2)
__global__ void scan_v5(const float* __restrict__ bcg, const bf16* __restrict__ xi,
                        const bf16* __restrict__ gz, const uint* __restrict__ pxg,
                        const float* __restrict__ A_log, const float* __restrict__ Dp,
                        const float* __restrict__ s0,
                        bf16* __restrict__ ypre, float* __restrict__ state_out)
{
  const int dg = blockIdx.x;
  const int tid = threadIdx.x;
  const int u = tid >> 7, ut = tid & 127;
  const int c = blockIdx.y*2 + u;
  const int dl = ut >> 3, ng = ut & 7;
  const int d0 = dg*16;
  const int d  = d0 + dl;
  const int base_m = c*PP;

  __shared__ float  bcT[2][3][16][36];   // B 0..15 | C 16..31, pitch 144B
  __shared__ uint   pxT[2][3][16][20];   // packed {dt(lo), dt*xi(hi)}, pitch 80B
  __shared__ ushort xgT[2][3][16][40];   // xi 0..15 | gz 16..31, pitch 80B
  __shared__ float  ybF[2][2][16][17];
  __shared__ ushort outT[2][16][24];     // pitch 48B
  __shared__ float  DvT[2][16];

  if (ut < 16) DvT[u][ut] = Dp[d0 + ut];
  const float2 al = *(const float2*)&A_log[(size_t)d*NST + 2*ng];
  const float a20 = -__expf(al.x)*LOG2E;
  const float a21 = -__expf(al.y)*LOG2E;
  float2 s = *(const float2*)&s0[((size_t)c*DIH + d)*NST + 2*ng];

  // staging roles: every thread 1 bcg float4 + 1 secondary uint4
  const int br = ut >> 3, bc4 = (ut & 7)*4;
  float4 bc_r; uint4 sec_r;

#define STAGE_LOAD(mm) do { \
    bc_r = *(const float4*)&bcg[(size_t)((mm) + br)*32 + bc4]; \
    if (ut < 64)      sec_r = *(const uint4*)&pxg[(size_t)((mm) + (ut>>2))*DIH + d0 + (ut&3)*4]; \
    else if (ut < 96) sec_r = *(const uint4*)&((const ushort*)xi)[(size_t)((mm) + ((ut-64)>>1))*DIH + d0 + ((ut-64)&1)*8]; \
    else              sec_r = *(const uint4*)&((const ushort*)gz)[(size_t)((mm) + ((ut-96)>>1))*DIH + d0 + ((ut-96)&1)*8]; \
  } while(0)
#define STAGE_COMMIT(nbuf) do { \
    *(float4*)&bcT[u][nbuf][br][bc4] = bc_r; \
    if (ut < 64)      *(uint4*)&pxT[u][nbuf][ut>>2][(ut&3)*4] = sec_r; \
    else if (ut < 96) *(uint4*)&xgT[u][nbuf][(ut-64)>>1][((ut-64)&1)*8] = sec_r; \
    else              *(uint4*)&xgT[u][nbuf][(ut-96)>>1][16 + ((ut-96)&1)*8] = sec_r; \
  } while(0)

  STAGE_LOAD(base_m);
  STAGE_COMMIT(0);
  __syncthreads();

  for (int g = 0; g < 16; ++g){
    const int buf = g % 3, nb = (g+1) % 3, yb = g & 1;
    const int m0 = base_m + g*16;
    if (g < 15) STAGE_LOAD(m0 + 16);
    // batch: pull tile data to registers, precompute decay/input terms
    float e0[16], e1[16], t0[16], t1[16], cx[16], cy[16];
    #pragma unroll
    for (int j = 0; j < 16; j++){
      const uint pk = pxT[u][buf][j][dl];
      const float2 Bv = *(const float2*)&bcT[u][buf][j][2*ng];
      const float2 Cv = *(const float2*)&bcT[u][buf][j][16 + 2*ng];
      const float dtv  = __int_as_float(pk << 16);
      const float dtxi = __int_as_float(pk & 0xffff0000u);
      e0[j] = __builtin_amdgcn_exp2f(dtv*a20);
      e1[j] = __builtin_amdgcn_exp2f(dtv*a21);
      t0[j] = dtxi*Bv.x; t1[j] = dtxi*Bv.y;
      cx[j] = Cv.x;      cy[j] = Cv.y;
    }
    // 16-step recurrence: pure fma chain; y/DPP tree hangs off it
    #pragma unroll
    for (int j = 0; j < 16; j++){
      s.x = fmaf(s.x, e0[j], t0[j]);
      s.y = fmaf(s.y, e1[j], t1[j]);
      float y = fmaf(s.y, cy[j], s.x*cx[j]);
      int t;
      t = __builtin_amdgcn_update_dpp(0, __float_as_int(y), 0x111, 0xf, 0xf, true);
      y += __int_as_float(t);
      t = __builtin_amdgcn_update_dpp(0, __float_as_int(y), 0x112, 0xf, 0xf, true);
      y += __int_as_float(t);
      t = __builtin_amdgcn_update_dpp(0, __float_as_int(y), 0x114, 0xf, 0xf, true);
      y += __int_as_float(t);
      if (ng == 7) ybF[u][yb][j][dl] = y;     // clean 8-lane group sum at lane 7/15
    }
    if (g < 15) STAGE_COMMIT(nb);
    __syncthreads();
    // epilogue: thread (ej=ut>>3, eg=ut&7) -> outputs (m0+ej, d0+2eg..2eg+1)
    {
      const int ej = ut >> 3, eg = ut & 7;
      #pragma unroll
      for (int q = 0; q < 2; q++){
        const int ed = 2*eg + q;
        bf16 xh; *(ushort*)&xh = xgT[u][buf][ej][ed];
        bf16 gh; *(ushort*)&gh = xgT[u][buf][ej][16+ed];
        bf16 hv = f2b((ybF[u][yb][ej][ed] + DvT[u][ed]*b2f(xh)) * b2f(gh));
        outT[u][ej][ed] = *(const ushort*)&hv;
      }
      if (eg < 2)
        *(uint4*)((ushort*)ypre + (size_t)(m0+ej)*DIH + d0 + eg*8) = *(const uint4*)&outT[u][ej][eg*8];
    }
  }
  *(float2*)&state_out[((size_t)c*DIH + d)*NST + 2*ng] = s;
#undef STAGE_LOAD
#undef STAGE_COMMIT
}

extern "C" void kernel_launch(void* const* d_in, const int* in_sizes, int n_in,
                              void* d_out, int out_size, void* d_ws, size_t ws_size,
                              hipStream_t stream) {
  const float* x       = (const float*)d_in[0];
  const float* s0      = (const float*)d_in[1];
  const float* in_w    = (const float*)d_in[2];
  const float* in_b    = (const float*)d_in[3];
  const float* conv_w  = (const float*)d_in[4];
  const float* conv_b  = (const float*)d_in[5];
  const float* param_w = (const float*)d_in[6];
  const float* param_b = (const float*)d_in[7];
  const float* dt_w    = (const float*)d_in[8];
  const float* dt_b    = (const float*)d_in[9];
  const float* out_w   = (const float*)d_in[10];
  const float* out_b   = (const float*)d_in[11];
  const float* A_log   = (const float*)d_in[12];
  const float* Dp      = (const float*)d_in[13];

  char* ws = (char*)d_ws;
  bf16*   xi    = (bf16*)ws;   ws += (size_t)MM*DIH*2;     //  8 MB
  bf16*   gz    = (bf16*)ws;   ws += (size_t)MM*DIH*2;     //  8 MB
  float*  bcg   = (float*)ws;  ws += (size_t)MM*32*4;      // 0.5 MB (B|C fp32)
  bf16*   xdbb  = (bf16*)ws;   ws += (size_t)MM*64*2;      // 0.5 MB (dt GEMM A)
  float*  cb2   = (float*)ws;  ws += 4096;                 //  4 KB
  bf16*   ypre  = (bf16*)ws;   ws += (size_t)MM*DIH*2;     //  8 MB
  bf16*   outwb = (bf16*)ws;   ws += (size_t)DMH*DIH*2;    //  1 MB
  bf16*   pwb   = (bf16*)ws;   ws += (size_t)64*DIH*2;     // 128 KB
  bf16*   dtwb  = (bf16*)ws;   ws += (size_t)DIH*64*2;     // 128 KB
  char*   U     = ws;          ws += (size_t)32*1024*1024; // union region, 32 MB
  // early tenants of U:
  bf16* Wfb  = (bf16*)(U);                                 // dead after conv GEMM
  bf16* xbf  = (bf16*)(U + (size_t) 4*1024*1024);          // dead after conv GEMM
  bf16* inwz = (bf16*)(U + (size_t) 8*1024*1024);
  bf16* inwT = (bf16*)(U + (size_t) 9*1024*1024);
  bf16* cwT  = (bf16*)(U + (size_t)10*1024*1024);          // dead after fold GEMM
  // late tenants of U:
  float* pxz = (float*)(U);                                // 8 MB split-K planes
  uint*  pxg = (uint*)(U + (size_t)16*1024*1024);          // 16 MB packed {dt, dt*xi}

  float* y_out  = (float*)d_out;                           // [C,P,DM] fp32
  float* st_out = y_out + (size_t)MM*DMH;                  // [C,DI,16] fp32

  hipMemsetAsync(cb2, 0, DIH*sizeof(float), stream);
  // fused prep (casts, conv repack + folded cb2, transpose, dt_w cast)
  prep_all<<<7424, 256, 0, stream>>>(x, in_w, out_w, param_w, conv_w, dt_w,
                                     in_b, conv_b, cb2,
                                     xbf, inwz, outwb, pwb, cwT, inwT, dtwb);

  // fold: Wf[k][o][m] = sum_i conv_w[o,i,k]*in_w[i,m]   (4 taps via grid.z)
  mfma_gemm<3,0,1><<<dim3(DIH/128, DMH/32, 4), 256, 0, stream>>>(
      cwT, DIH, inwT, DIH, nullptr, nullptr, Wfb, 4*DMH, DIH, DIH*DIH, DMH, 0);
  // z-half in_proj: gelu(gelu(x @ in_w_z^T + b_z)) -> gz (contiguous bf16)
  mfma_gemm<2,0,1><<<dim3(MM/128, DIH/32), 256, 0, stream>>>(
      xbf, DMH, inwz, DMH, in_b + DIH, nullptr, gz, DIH, DMH, 0, 0, 0);
  // fused conv: gelu( sum_tap x[clamp] @ Wf_tap^T + cb2 ) -> xi (contiguous bf16)
  mfma_gemm<1,1,1><<<dim3(MM/128, DIH/32), 256, 0, stream>>>(
      xbf, DMH, Wfb, 4*DMH, cb2, nullptr, xi, DIH, 4*DMH, 0, 0, 0);
  // x_db = xi @ param_w.T (split-K=8, per-z plane writes; bias added in reduce)
  mfma_gemm<6,0,1><<<dim3(MM/128, 2, 8), 256, 0, stream>>>(
      xi, DIH, pwb, DIH, nullptr, pxz, nullptr, 64, 128, 0, MM*64, 128);
  // reduce planes + param_b -> xdbb (bf16 dt input, K=64 pad) + bcg (fp32 B|C)
  reduce_cast<<<256, 256, 0, stream>>>(pxz, param_b, bcg, xdbb);
  // pxg[m][d] = pack{ softplus(dt_in @ dt_w^T + dt_b), dt * xi }  via MFMA
  mfma_gemm<5,0,1><<<dim3(MM/128, DIH/32), 256, 0, stream>>>(
      xdbb, 64, dtwb, 64, dt_b, (float*)xi, (bf16*)pxg, DIH, 64, 0, 0, 0);
  // fused scan, 2 states/lane, 2 units/block, tile register batching
  scan_v5<<<dim3(64, CC/2), 256, 0, stream>>>(bcg, xi, gz, pxg, A_log, Dp,
                                              s0, ypre, st_out);
  // out projection
  mfma_gemm<0,0,1><<<dim3(MM/128, DMH/32), 256, 0, stream>>>(
      ypre, DIH, outwb, DIH, out_b, y_out, nullptr, DMH, DIH, 0, 0, 0);
}

// Round 9
// 217.907 us; speedup vs baseline: 1.4904x; 1.0309x over previous
//
#include <hip/hip_runtime.h>
#include <hip/hip_bf16.h>

typedef __hip_bfloat16 bf16;
typedef short bf16x8 __attribute__((ext_vector_type(8)));
typedef float f32x4 __attribute__((ext_vector_type(4)));

#define CC 16
#define PP 256
#define DMH 512
#define DIH 1024
#define MM (CC*PP)   /* 4096 rows (c,p) */
#define NST 16
#define NDT 32
#define LOG2E 1.44269504088896f

__device__ __forceinline__ float b2f(bf16 v){ return __bfloat162float(v); }
__device__ __forceinline__ bf16  f2b(float v){ return __float2bfloat16(v); }
__device__ __forceinline__ float us2f(ushort u){ bf16 h; *(ushort*)&h = u; return __bfloat162float(h); }

// fast tanh-gelu: tanh(u) = 1 - 2/(exp(2u)+1); exact limits at +-inf
__device__ __forceinline__ float geluf(float x){
  const float u = x*(0.7978845608028654f + 0.035677408136300125f*x*x);
  const float e = __builtin_amdgcn_exp2f(2.885390081777927f*u);   // exp(2u)
  const float t = 1.0f - 2.0f*__builtin_amdgcn_rcpf(e + 1.0f);
  return 0.5f*x*(1.0f + t);
}
// softplus via v_exp/v_log: ln(1+e^x) = ln2 * log2(1 + exp2(x*log2e))
__device__ __forceinline__ float softplusf(float x){
  if (x > 20.0f) return x;
  const float e = __builtin_amdgcn_exp2f(x * LOG2E);
  return 0.6931471805599453f * __builtin_amdgcn_logf(1.0f + e);
}

__device__ __forceinline__ void g2l16(const bf16* g, bf16* l){
  __builtin_amdgcn_global_load_lds(
      (const __attribute__((address_space(1))) void*)g,
      (__attribute__((address_space(3))) void*)(uint32_t)(uintptr_t)l,
      16, 0, 0);
}

// ---------------- fused prep: casts + conv repack (+cb2 fold) + transpose + dtw cast --
__global__ void prep_all(const float* __restrict__ x, const float* __restrict__ in_w,
                         const float* __restrict__ out_w, const float* __restrict__ param_w,
                         const float* __restrict__ conv_w, const float* __restrict__ dt_w,
                         const float* __restrict__ in_b, const float* __restrict__ conv_b,
                         float* __restrict__ cb2,
                         bf16* __restrict__ xbf, bf16* __restrict__ inwz,
                         bf16* __restrict__ outwb, bf16* __restrict__ pwb,
                         bf16* __restrict__ cwT, bf16* __restrict__ inwT,
                         bf16* __restrict__ dtwb)
{
  const int b = blockIdx.x, tid = threadIdx.x;
  if (b < 3136){
    const float* src; bf16* dst; int i;
    if (b < 2048)      { src = x;                       dst = xbf;   i = b*256 + tid; }
    else if (b < 2560) { src = in_w + (size_t)DIH*DMH;  dst = inwz;  i = (b-2048)*256 + tid; }
    else if (b < 3072) { src = out_w;                   dst = outwb; i = (b-2560)*256 + tid; }
    else               { src = param_w;                 dst = pwb;   i = (b-3072)*256 + tid; }
    float4 v = ((const float4*)src)[i];
    bf16 o[4] = {f2b(v.x), f2b(v.y), f2b(v.z), f2b(v.w)};
    *(ushort4*)&dst[(size_t)i*4] = *(const ushort4*)o;
  } else if (b < 7232){
    const size_t idx = (size_t)(b-3136)*256 + tid;      // o*1024 + i
    const float4 v = *(const float4*)(conv_w + idx*4);  // [o][i][tap] -> [tap][o][i]
    cwT[idx]                     = f2b(v.x);
    cwT[(size_t)DIH*DIH   + idx] = f2b(v.y);
    cwT[(size_t)2*DIH*DIH + idx] = f2b(v.z);
    cwT[(size_t)3*DIH*DIH + idx] = f2b(v.w);
    // folded bias partial: cb2[o] += sum_i (sum_k w[o,i,k]) * in_b[i]
    __shared__ float ls[4];
    const int i = (int)(idx & 1023);
    float acc = (v.x + v.y + v.z + v.w) * in_b[i];
    for (int off = 32; off; off >>= 1) acc += __shfl_down(acc, off);
    if ((tid & 63) == 0) ls[tid >> 6] = acc;
    __syncthreads();
    if (tid == 0){
      const int o = (int)(idx >> 10);
      float tot = ls[0] + ls[1] + ls[2] + ls[3];
      if (((b - 3136) & 3) == 0) tot += conv_b[o];
      atomicAdd(&cb2[o], tot);
    }
  } else if (b < 7360){
    // in_w xi-half [i<1024][m<512] -> inwT [m][i], 64x64 LDS tile
    __shared__ float T[64][65];
    const int b2 = b - 7232;
    const int i0 = (b2 >> 3)*64, m0 = (b2 & 7)*64;
    const int r = tid >> 2, c0 = (tid & 3)*16;
    #pragma unroll
    for (int t = 0; t < 4; t++){
      float4 v = *(const float4*)&in_w[(size_t)(i0 + r)*DMH + m0 + c0 + t*4];
      T[r][c0+t*4+0] = v.x; T[r][c0+t*4+1] = v.y;
      T[r][c0+t*4+2] = v.z; T[r][c0+t*4+3] = v.w;
    }
    __syncthreads();
    bf16 o[16];
    #pragma unroll
    for (int t = 0; t < 16; t++) o[t] = f2b(T[c0 + t][r]);
    *(ushort4*)&inwT[(size_t)(m0 + r)*DIH + i0 + c0]      = *(const ushort4*)&o[0];
    *(ushort4*)&inwT[(size_t)(m0 + r)*DIH + i0 + c0 + 4]  = *(const ushort4*)&o[4];
    *(ushort4*)&inwT[(size_t)(m0 + r)*DIH + i0 + c0 + 8]  = *(const ushort4*)&o[8];
    *(ushort4*)&inwT[(size_t)(m0 + r)*DIH + i0 + c0 + 12] = *(const ushort4*)&o[12];
  } else {
    // dt_w [1024][32] fp32 -> dtwb [1024][64] bf16, cols 32..63 zero (K=64 pad)
    const int idx4 = (b-7360)*256 + tid;          // 0..16383
    const int d = idx4 >> 4, k4 = (idx4 & 15)*4;
    bf16 o[4] = {};
    if (k4 < 32){
      const float4 v = *(const float4*)&dt_w[(size_t)d*NDT + k4];
      o[0]=f2b(v.x); o[1]=f2b(v.y); o[2]=f2b(v.z); o[3]=f2b(v.w);
    }
    *(ushort4*)&dtwb[(size_t)d*64 + k4] = *(const ushort4*)o;
  }
}

// reduce 4 split-K planes + param_b -> xdbb (bf16 cols 0..31, K=64 pad) + bcg (fp32 B|C)
__global__ void reduce_cast(const float* __restrict__ pxz, const float* __restrict__ param_b,
                            float* __restrict__ bcg, bf16* __restrict__ xdbb){
  const int idx = blockIdx.x*256 + threadIdx.x;   // 0..65535 float4 units
  const int m = idx >> 4, k4 = (idx & 15)*4;
  float4 s = make_float4(0.f,0.f,0.f,0.f);
  #pragma unroll
  for (int z = 0; z < 4; z++){
    const float4 v = *(const float4*)&pxz[(size_t)z*MM*64 + (size_t)m*64 + k4];
    s.x += v.x; s.y += v.y; s.z += v.z; s.w += v.w;
  }
  const float4 pb = *(const float4*)&param_b[k4];
  s.x += pb.x; s.y += pb.y; s.z += pb.z; s.w += pb.w;
  if (k4 < 32){
    bf16 o[4] = {f2b(s.x), f2b(s.y), f2b(s.z), f2b(s.w)};
    *(ushort4*)&xdbb[(size_t)m*64 + k4] = *(const ushort4*)o;
  } else {
    bf16 o[4] = {};
    *(ushort4*)&xdbb[(size_t)m*64 + k4] = *(const ushort4*)o;  // K pad
    *(float4*)&bcg[(size_t)m*32 + (k4 - 32)] = s;
  }
}

// ---------------- MFMA GEMM: C[m,n] = epi( sum_k A[m,k]*B[n,k] + bias[n] ) -------------
// LDS XOR-swizzle (T2, gload_lds-compatible): linear LDS dest, pre-swizzled global
// source chunk, same XOR on the ds_read side.
#define TBK 64

template<int EPI, int NFRAG>
__launch_bounds__(256)
__global__ void mfma_gemm(const bf16* __restrict__ A, int lda,
                          const bf16* __restrict__ B, int ldb,
                          const float* __restrict__ bias,
                          float* __restrict__ outF,
                          bf16* __restrict__ outB0,
                          int ldo, int K, int azs, int ozs, int kzs)
{
  __shared__ bf16 As[128*TBK];           // 16 KB
  __shared__ bf16 Bs[32*NFRAG*TBK];      // 4/8 KB
  const int tid  = threadIdx.x;
  const int lane = tid & 63;
  const int wave = tid >> 6;
  const int wr = (wave >> 1) * 64;
  const int wc = (wave & 1) * 16 * NFRAG;
  const int mBase = blockIdx.x * 128;
  const int nBase = blockIdx.y * (32*NFRAG);
  A += (size_t)blockIdx.z * azs;
  const int nOff = blockIdx.z * ozs;
  const int koff = blockIdx.z * kzs;

  f32x4 acc[4][NFRAG] = {};

  for (int k0 = 0; k0 < K; k0 += TBK) {
    __syncthreads();
    #pragma unroll
    for (int it = 0; it < 4; it++) {      // As: 1024 chunks of 16B
      const int idx = it*256 + tid;
      const int r = idx >> 3;
      const int cs = (idx & 7) ^ (r & 7);         // pre-swizzled source chunk
      const bf16* ga = A + (size_t)(mBase + r)*lda + koff + k0 + cs*8;
      g2l16(ga, &As[(size_t)idx*8]);
    }
    #pragma unroll
    for (int it = 0; it < NFRAG; it++) {  // Bs: 256*NFRAG chunks of 16B
      const int idx = it*256 + tid;
      const int r = idx >> 3;
      const int cs = (idx & 7) ^ (r & 7);
      const bf16* gb = B + (size_t)(nBase + r)*ldb + koff + k0 + cs*8;
      g2l16(gb, &Bs[(size_t)idx*8]);
    }
    __syncthreads();
    #pragma unroll
    for (int ks = 0; ks < 2; ks++) {
      bf16x8 af[4], bfr[NFRAG];
      #pragma unroll
      for (int r = 0; r < 4; r++){
        const int rr = wr + r*16 + (lane & 15);
        const int ch = (ks*4 + (lane>>4)) ^ (rr & 7);
        af[r] = *(const bf16x8*)&As[rr*TBK + ch*8];
      }
      #pragma unroll
      for (int c = 0; c < NFRAG; c++){
        const int rn = wc + c*16 + (lane & 15);
        const int ch = (ks*4 + (lane>>4)) ^ (rn & 7);
        bfr[c] = *(const bf16x8*)&Bs[rn*TBK + ch*8];
      }
      #pragma unroll
      for (int r = 0; r < 4; r++)
        #pragma unroll
        for (int c = 0; c < NFRAG; c++)
          acc[r][c] = __builtin_amdgcn_mfma_f32_16x16x32_bf16(af[r], bfr[c], acc[r][c], 0, 0, 0);
    }
  }

  const int col0 = lane & 15;
  const int row0 = (lane >> 4) * 4;
  #pragma unroll
  for (int r = 0; r < 4; r++) {
    #pragma unroll
    for (int c = 0; c < NFRAG; c++) {
      #pragma unroll
      for (int reg = 0; reg < 4; reg++) {
        const int m = mBase + wr + r*16 + row0 + reg;
        const int n = nBase + wc + c*16 + col0;
        const float av = acc[r][c][reg];
        if (EPI == 0) {
          outF[(size_t)m*ldo + n] = av + bias[n];
        } else if (EPI == 2) {
          outB0[(size_t)m*ldo + n] = f2b(geluf(geluf(av + bias[n])));
        } else if (EPI == 3) {
          outB0[(size_t)m*ldo + n + nOff] = f2b(av);
        } else if (EPI == 5) {
          // dt = softplus(av + dt_b[n]) -> bf16 dt-only plane (dt*xi done in scan)
          const float dtv = softplusf(av + bias[n]);
          bf16 dh = f2b(dtv);
          ((ushort*)outB0)[(size_t)m*ldo + n] = *(const ushort*)&dh;
        } else if (EPI == 6) {
          outF[(size_t)m*ldo + n + nOff] = av;       // split-K plane write (no atomics)
        }
      }
    }
  }
}

// ---------------- halo-tiled conv GEMM: xi = gelu( sum_tap x[clamp]@Wf_tap^T + cb2 ) ---
// Stages the A panel ONCE per K-step (132-row halo tile, edge-clamped) and keeps 4
// tap-accumulators: K-loop 32 -> 8 rounds, A staging traffic / 4, barriers / 4.
__launch_bounds__(256)
__global__ void mfma_conv(const bf16* __restrict__ A,   // xbf [4096][512]
                          const bf16* __restrict__ B,   // Wfb [1024][4*512] (o, tap*512+m)
                          const float* __restrict__ bias, // cb2
                          bf16* __restrict__ outB)      // xi [4096][1024]
{
  __shared__ bf16 As[132*64];        // halo rows h=0..131 -> p = clamp(q-2+h, 0, 255)
  __shared__ bf16 Bs[128*64];        // (tap*32+o) x 64
  const int tid = threadIdx.x;
  const int lane = tid & 63;
  const int wave = tid >> 6;
  const int wr = (wave >> 1) * 64;
  const int wc = (wave & 1) * 16;
  const int mBase = blockIdx.x * 128;
  const int nBase = blockIdx.y * 32;
  const int cc = mBase >> 8;
  const int q  = mBase & 255;

  f32x4 acc[4][4] = {};   // [r][tap]

  for (int k0 = 0; k0 < DMH; k0 += 64) {
    __syncthreads();
    // stage A halo: 132 rows x 8 chunks = 1056 (swizzle keyed on halo row h)
    #pragma unroll
    for (int it = 0; it < 5; it++) {
      const int idx = it*256 + tid;
      if (it < 4 || idx < 1056) {
        const int h = idx >> 3;
        const int cs = (idx & 7) ^ (h & 7);
        int p = q - 2 + h;
        p = min(max(p, 0), PP-1);
        g2l16(A + ((size_t)(cc*PP + p))*DMH + k0 + cs*8, &As[(size_t)idx*8]);
      }
    }
    // stage B: rows (tap*32+o), 128 x 8 chunks = 1024
    #pragma unroll
    for (int it = 0; it < 4; it++) {
      const int idx = it*256 + tid;
      const int r = idx >> 3;             // tap*32 + o
      const int tap = r >> 5, o = r & 31;
      const int cs = (idx & 7) ^ (r & 7);
      g2l16(B + (size_t)(nBase + o)*(4*DMH) + tap*DMH + k0 + cs*8, &Bs[(size_t)idx*8]);
    }
    __syncthreads();
    #pragma unroll
    for (int ks = 0; ks < 2; ks++) {
      #pragma unroll
      for (int t = 0; t < 4; t++) {
        bf16x8 bft;
        {
          const int rn = t*32 + wc + (lane & 15);
          const int ch = (ks*4 + (lane>>4)) ^ (rn & 7);
          bft = *(const bf16x8*)&Bs[rn*64 + ch*8];
        }
        #pragma unroll
        for (int r = 0; r < 4; r++) {
          const int h = wr + r*16 + (lane & 15) + t;   // output row m_local + tap
          const int ch = (ks*4 + (lane>>4)) ^ (h & 7);
          bf16x8 af = *(const bf16x8*)&As[h*64 + ch*8];
          acc[r][t] = __builtin_amdgcn_mfma_f32_16x16x32_bf16(af, bft, acc[r][t], 0, 0, 0);
        }
      }
    }
  }
  const int col0 = lane & 15;
  const int row0 = (lane >> 4) * 4;
  #pragma unroll
  for (int r = 0; r < 4; r++) {
    #pragma unroll
    for (int reg = 0; reg < 4; reg++) {
      const int m = mBase + wr + r*16 + row0 + reg;
      const int n = nBase + wc + col0;
      const float av = acc[r][0][reg] + acc[r][1][reg] + acc[r][2][reg] + acc[r][3][reg];
      outB[(size_t)m*DIH + n] = f2b(geluf(av + bias[n]));
    }
  }
}

// ---------------- fused scan: 2 states/lane, tile register batching, dt-only plane ----
__launch_bounds__(256, 2)
__global__ void scan_v5(const float* __restrict__ bcg, const bf16* __restrict__ xi,
                        const bf16* __restrict__ gz, const bf16* __restrict__ dtp,
                        const float* __restrict__ A_log, const float* __restrict__ Dp,
                        const float* __restrict__ s0,
                        bf16* __restrict__ ypre, float* __restrict__ state_out)
{
  const int dg = blockIdx.x;
  const int tid = threadIdx.x;
  const int u = tid >> 7, ut = tid & 127;
  const int c = blockIdx.y*2 + u;
  const int dl = ut >> 3, ng = ut & 7;
  const int d0 = dg*16;
  const int d  = d0 + dl;
  const int base_m = c*PP;

  __shared__ float  bcT[2][3][16][36];   // B 0..15 | C 16..31, pitch 144B
  __shared__ ushort dtT[2][3][16][24];   // bf16 dt, pitch 48B
  __shared__ ushort xgT[2][3][16][40];   // xi 0..15 | gz 16..31, pitch 80B
  __shared__ float  ybF[2][2][16][17];
  __shared__ ushort outT[2][16][24];     // pitch 48B
  __shared__ float  DvT[2][16];

  if (ut < 16) DvT[u][ut] = Dp[d0 + ut];
  const float2 al = *(const float2*)&A_log[(size_t)d*NST + 2*ng];
  const float a20 = -__expf(al.x)*LOG2E;
  const float a21 = -__expf(al.y)*LOG2E;
  float2 s = *(const float2*)&s0[((size_t)c*DIH + d)*NST + 2*ng];

  // staging roles: all 128 threads 1 bcg float4; ut<96 one secondary uint4
  const int br = ut >> 3, bc4 = (ut & 7)*4;
  float4 bc_r; uint4 sec_r;

#define STAGE_LOAD(mm) do { \
    bc_r = *(const float4*)&bcg[(size_t)((mm) + br)*32 + bc4]; \
    if (ut < 32)      sec_r = *(const uint4*)&((const ushort*)dtp)[(size_t)((mm) + (ut>>1))*DIH + d0 + (ut&1)*8]; \
    else if (ut < 64) sec_r = *(const uint4*)&((const ushort*)xi)[(size_t)((mm) + ((ut-32)>>1))*DIH + d0 + ((ut-32)&1)*8]; \
    else if (ut < 96) sec_r = *(const uint4*)&((const ushort*)gz)[(size_t)((mm) + ((ut-64)>>1))*DIH + d0 + ((ut-64)&1)*8]; \
  } while(0)
#define STAGE_COMMIT(nbuf) do { \
    *(float4*)&bcT[u][nbuf][br][bc4] = bc_r; \
    if (ut < 32)      *(uint4*)&dtT[u][nbuf][ut>>1][(ut&1)*8] = sec_r; \
    else if (ut < 64) *(uint4*)&xgT[u][nbuf][(ut-32)>>1][((ut-32)&1)*8] = sec_r; \
    else if (ut < 96) *(uint4*)&xgT[u][nbuf][(ut-64)>>1][16 + ((ut-64)&1)*8] = sec_r; \
  } while(0)

  STAGE_LOAD(base_m);
  STAGE_COMMIT(0);
  __syncthreads();

  for (int g = 0; g < 16; ++g){
    const int buf = g % 3, nb = (g+1) % 3, yb = g & 1;
    const int m0 = base_m + g*16;
    if (g < 15) STAGE_LOAD(m0 + 16);
    // batch: pull tile data to registers, precompute decay/input terms
    float e0[16], e1[16], t0[16], t1[16], cx[16], cy[16];
    #pragma unroll
    for (int j = 0; j < 16; j++){
      const float dtv = us2f(dtT[u][buf][j][dl]);
      const float xiv = us2f(xgT[u][buf][j][dl]);
      const float2 Bv = *(const float2*)&bcT[u][buf][j][2*ng];
      const float2 Cv = *(const float2*)&bcT[u][buf][j][16 + 2*ng];
      const float dtxi = dtv * xiv;
      e0[j] = __builtin_amdgcn_exp2f(dtv*a20);
      e1[j] = __builtin_amdgcn_exp2f(dtv*a21);
      t0[j] = dtxi*Bv.x; t1[j] = dtxi*Bv.y;
      cx[j] = Cv.x;      cy[j] = Cv.y;
    }
    // 16-step recurrence: pure fma chain; y/DPP tree hangs off it
    #pragma unroll
    for (int j = 0; j < 16; j++){
      s.x = fmaf(s.x, e0[j], t0[j]);
      s.y = fmaf(s.y, e1[j], t1[j]);
      float y = fmaf(s.y, cy[j], s.x*cx[j]);
      int t;
      t = __builtin_amdgcn_update_dpp(0, __float_as_int(y), 0x111, 0xf, 0xf, true);
      y += __int_as_float(t);
      t = __builtin_amdgcn_update_dpp(0, __float_as_int(y), 0x112, 0xf, 0xf, true);
      y += __int_as_float(t);
      t = __builtin_amdgcn_update_dpp(0, __float_as_int(y), 0x114, 0xf, 0xf, true);
      y += __int_as_float(t);
      if (ng == 7) ybF[u][yb][j][dl] = y;     // clean 8-lane group sum at lane 7/15
    }
    if (g < 15) STAGE_COMMIT(nb);
    __syncthreads();
    // epilogue: thread (ej=ut>>3, eg=ut&7) -> outputs (m0+ej, d0+2eg..2eg+1)
    {
      const int ej = ut >> 3, eg = ut & 7;
      #pragma unroll
      for (int q = 0; q < 2; q++){
        const int ed = 2*eg + q;
        bf16 hv = f2b((ybF[u][yb][ej][ed] + DvT[u][ed]*us2f(xgT[u][buf][ej][ed]))
                      * us2f(xgT[u][buf][ej][16+ed]));
        outT[u][ej][ed] = *(const ushort*)&hv;
      }
      if (eg < 2)
        *(uint4*)((ushort*)ypre + (size_t)(m0+ej)*DIH + d0 + eg*8) = *(const uint4*)&outT[u][ej][eg*8];
    }
  }
  *(float2*)&state_out[((size_t)c*DIH + d)*NST + 2*ng] = s;
#undef STAGE_LOAD
#undef STAGE_COMMIT
}

extern "C" void kernel_launch(void* const* d_in, const int* in_sizes, int n_in,
                              void* d_out, int out_size, void* d_ws, size_t ws_size,
                              hipStream_t stream) {
  const float* x       = (const float*)d_in[0];
  const float* s0      = (const float*)d_in[1];
  const float* in_w    = (const float*)d_in[2];
  const float* in_b    = (const float*)d_in[3];
  const float* conv_w  = (const float*)d_in[4];
  const float* conv_b  = (const float*)d_in[5];
  const float* param_w = (const float*)d_in[6];
  const float* param_b = (const float*)d_in[7];
  const float* dt_w    = (const float*)d_in[8];
  const float* dt_b    = (const float*)d_in[9];
  const float* out_w   = (const float*)d_in[10];
  const float* out_b   = (const float*)d_in[11];
  const float* A_log   = (const float*)d_in[12];
  const float* Dp      = (const float*)d_in[13];

  char* ws = (char*)d_ws;
  bf16*   xi    = (bf16*)ws;   ws += (size_t)MM*DIH*2;     //  8 MB
  bf16*   gz    = (bf16*)ws;   ws += (size_t)MM*DIH*2;     //  8 MB
  float*  bcg   = (float*)ws;  ws += (size_t)MM*32*4;      // 0.5 MB (B|C fp32)
  bf16*   xdbb  = (bf16*)ws;   ws += (size_t)MM*64*2;      // 0.5 MB (dt GEMM A)
  float*  cb2   = (float*)ws;  ws += 4096;                 //  4 KB
  bf16*   ypre  = (bf16*)ws;   ws += (size_t)MM*DIH*2;     //  8 MB
  bf16*   outwb = (bf16*)ws;   ws += (size_t)DMH*DIH*2;    //  1 MB
  bf16*   pwb   = (bf16*)ws;   ws += (size_t)64*DIH*2;     // 128 KB
  bf16*   dtwb  = (bf16*)ws;   ws += (size_t)DIH*64*2;     // 128 KB
  char*   U     = ws;          ws += (size_t)32*1024*1024; // union region, 32 MB
  // early tenants of U:
  bf16* Wfb  = (bf16*)(U);                                 // dead after conv
  bf16* xbf  = (bf16*)(U + (size_t) 4*1024*1024);          // dead after conv
  bf16* inwz = (bf16*)(U + (size_t) 8*1024*1024);
  bf16* inwT = (bf16*)(U + (size_t) 9*1024*1024);
  bf16* cwT  = (bf16*)(U + (size_t)10*1024*1024);          // dead after fold GEMM
  // late tenants of U:
  float* pxz = (float*)(U);                                // 4 MB split-K planes
  bf16*  dtp = (bf16*)(U + (size_t)16*1024*1024);          // 8 MB bf16 dt plane

  float* y_out  = (float*)d_out;                           // [C,P,DM] fp32
  float* st_out = y_out + (size_t)MM*DMH;                  // [C,DI,16] fp32

  hipMemsetAsync(cb2, 0, DIH*sizeof(float), stream);
  // fused prep (casts, conv repack + folded cb2, transpose, dt_w cast)
  prep_all<<<7424, 256, 0, stream>>>(x, in_w, out_w, param_w, conv_w, dt_w,
                                     in_b, conv_b, cb2,
                                     xbf, inwz, outwb, pwb, cwT, inwT, dtwb);

  // fold: Wf[k][o][m] = sum_i conv_w[o,i,k]*in_w[i,m]   (4 taps via grid.z)
  mfma_gemm<3,1><<<dim3(DIH/128, DMH/32, 4), 256, 0, stream>>>(
      cwT, DIH, inwT, DIH, nullptr, nullptr, Wfb, 4*DMH, DIH, DIH*DIH, DMH, 0);
  // z-half in_proj: gelu(gelu(x @ in_w_z^T + b_z)) -> gz (contiguous bf16)
  mfma_gemm<2,1><<<dim3(MM/128, DIH/32), 256, 0, stream>>>(
      xbf, DMH, inwz, DMH, in_b + DIH, nullptr, gz, DIH, DMH, 0, 0, 0);
  // fused conv via halo-tiled kernel (A staged once, 4 tap-accumulators)
  mfma_conv<<<dim3(MM/128, DIH/32), 256, 0, stream>>>(xbf, Wfb, cb2, xi);
  // x_db = xi @ param_w.T (split-K=4, per-z plane writes; bias added in reduce)
  mfma_gemm<6,1><<<dim3(MM/128, 2, 4), 256, 0, stream>>>(
      xi, DIH, pwb, DIH, nullptr, pxz, nullptr, 64, 256, 0, MM*64, 256);
  // reduce planes + param_b -> xdbb (bf16 dt input, K=64 pad) + bcg (fp32 B|C)
  reduce_cast<<<256, 256, 0, stream>>>(pxz, param_b, bcg, xdbb);
  // dtp[m][d] = bf16( softplus(dt_in @ dt_w^T + dt_b) )  via MFMA
  mfma_gemm<5,1><<<dim3(MM/128, DIH/32), 256, 0, stream>>>(
      xdbb, 64, dtwb, 64, dt_b, nullptr, (bf16*)dtp, DIH, 64, 0, 0, 0);
  // fused scan, 2 states/lane, 2 units/block, tile register batching
  scan_v5<<<dim3(64, CC/2), 256, 0, stream>>>(bcg, xi, gz, dtp, A_log, Dp,
                                              s0, ypre, st_out);
  // out projection
  mfma_gemm<0,1><<<dim3(MM/128, DMH/32), 256, 0, stream>>>(
      ypre, DIH, outwb, DIH, out_b, y_out, nullptr, DMH, DIH, 0, 0, 0);
}